// Round 12
// baseline (625.274 us; speedup 1.0000x reference)
//
#include <hip/hip_runtime.h>
#include <hip/hip_bf16.h>
#include <math.h>

// Problem constants
#define TK 1024      // tokens
#define HD 1024      // hidden
#define NF3 3072     // shared ffn dim
#define NF2 2048     // routed ffn dim
#define NSH 8        // shared experts
#define NEX 32       // routed experts
#define KSEL 4       // top-k
#define RRK 64       // router rank

typedef short bf16x8 __attribute__((ext_vector_type(8)));
typedef float f32x4 __attribute__((ext_vector_type(4)));
typedef unsigned short u16;

__device__ __forceinline__ u16 f2b(float f){
  union{float f; unsigned u;} c; c.f=f;
  unsigned r = c.u + 0x7FFFu + ((c.u>>16)&1u);
  return (u16)(r>>16);
}

__device__ __forceinline__ unsigned pk2(float a, float b){
  __hip_bfloat162 h = __float22bfloat162_rn(float2{a, b});
  union{__hip_bfloat162 h; unsigned u;} c; c.h = h; return c.u;
}

// XOR swizzle for [row][64k] bf16 LDS tiles (128B rows, 8 chunks of 16B)
__device__ __forceinline__ int swz8(int row, int c){
  return row*128 + ((c ^ (row&7))<<4);
}

// scratch fp32 [64k][64n] tile helpers (involutive chunk perm)
__device__ __forceinline__ int scrofs(int k, int nq){
  return k*256 + (((nq&8) | ((nq&7)^(k&7)))<<4);
}
__device__ __forceinline__ int chunkperm(int c, int k){
  return (c&8) | ((c&7)^(k&7));
}

#define GLDS16(gptr, lptr) \
  __builtin_amdgcn_global_load_lds((const __attribute__((address_space(1))) unsigned*)(gptr), \
                                   (__attribute__((address_space(3))) unsigned*)(lptr), 16, 0, 0)

// ---------------- small kernels ----------------

__global__ void init_kernel(int* counts, int* cursors){
  int i = threadIdx.x;
  if (i < NEX){ counts[i]=0; cursors[i]=0; }
}

// compute r per token; write xb = bf16(x), rvec[t]=r. If XNB: also xnb + out=x (fallback).
__global__ void rms_kernel(const float* __restrict__ x, const float* __restrict__ sn,
                           u16* __restrict__ xb, u16* __restrict__ xnb,
                           float* __restrict__ out, float* __restrict__ rvec, int writeXnb)
{
  const int t = blockIdx.x, tid = threadIdx.x;
  const float4 v = ((const float4*)(x + (size_t)t*HD))[tid];
  float ss = v.x*v.x + v.y*v.y + v.z*v.z + v.w*v.w;
  #pragma unroll
  for (int m=32;m>=1;m>>=1) ss += __shfl_xor(ss, m);
  __shared__ float red[4];
  if ((tid&63)==0) red[tid>>6]=ss;
  __syncthreads();
  const float r = rsqrtf((red[0]+red[1]+red[2]+red[3])*(1.0f/HD) + 1e-6f);
  if (tid==0) rvec[t] = r;
  ushort4 o; o.x=f2b(v.x); o.y=f2b(v.y); o.z=f2b(v.z); o.w=f2b(v.w);
  ((ushort4*)(xb + (size_t)t*HD))[tid] = o;
  if (writeXnb){
    ((float4*)(out + (size_t)t*HD))[tid] = v;
    #pragma unroll
    for (int s=0;s<NSH;s++){
      const float4 g = ((const float4*)(sn + (size_t)s*HD))[tid];
      ushort4 q;
      q.x=f2b(v.x*r*g.x); q.y=f2b(v.y*r*g.y); q.z=f2b(v.z*r*g.z); q.w=f2b(v.w*r*g.w);
      ((ushort4*)(xnb + ((size_t)s*TK + t)*HD))[tid] = q;
    }
  }
}

__global__ void router_kernel(const float* __restrict__ x, const float* __restrict__ rd,
                              const float* __restrict__ ru,
                              int* __restrict__ sel, float* __restrict__ wts,
                              int* __restrict__ counts)
{
  const int t = blockIdx.x, l = threadIdx.x;
  __shared__ float xl[HD];
  __shared__ float xr[RRK];
  __shared__ float lg[NEX];
  const float* xrow = x + (size_t)t*HD;
  for (int i=l;i<HD;i+=64) xl[i]=xrow[i];
  __syncthreads();
  float acc=0.f;
  for (int h=0;h<HD;h++) acc += xl[h]*rd[h*RRK + l];
  xr[l]=acc;
  __syncthreads();
  if (l < NEX){
    float a=0.f;
    for (int r=0;r<RRK;r++) a += xr[r]*ru[r*NEX + l];
    lg[l]=a;
  }
  __syncthreads();
  if (l==0){
    int   sk[KSEL]; float val[KSEL]; unsigned used=0;
    for (int k=0;k<KSEL;k++){
      float best=-1e30f; int bi=0;
      for (int e=0;e<NEX;e++){
        if (used & (1u<<e)) continue;
        if (lg[e] > best){ best=lg[e]; bi=e; }
      }
      used |= (1u<<bi); sk[k]=bi; val[k]=best;
    }
    const float m = val[0];
    float w[KSEL], s=0.f;
    for (int k=0;k<KSEL;k++){ w[k]=expf(val[k]-m); s+=w[k]; }
    for (int k=0;k<KSEL;k++){
      sel[t*KSEL+k]=sk[k]; wts[t*KSEL+k]=w[k]/s;
      atomicAdd(&counts[sk[k]], 1);
    }
  }
}

__global__ void scan_loss_kernel(const int* __restrict__ counts, int* __restrict__ offsets,
                                 float* __restrict__ out_loss)
{
  if (threadIdx.x==0){
    int off=0; float var=0.f;
    for (int e=0;e<NEX;e++){
      offsets[e]=off; off+=counts[e];
      float d = (float)counts[e] - 128.0f;
      var += d*d;
    }
    out_loss[0] = var * (1.0f/31.0f);
  }
}

__global__ void scatter_kernel(const int* __restrict__ sel, const float* __restrict__ wts,
                               const int* __restrict__ offsets, int* __restrict__ cursors,
                               int* __restrict__ tok_of, float* __restrict__ wt_of,
                               int* __restrict__ slot_of)
{
  const int id = blockIdx.x*256 + threadIdx.x;
  const int e = sel[id];
  const int pos = atomicAdd(&cursors[e], 1);
  const int slot = offsets[e] + pos;
  tok_of[slot] = id >> 2;
  wt_of[slot]  = wts[id];
  slot_of[id]  = slot;
}

// transpose-convert: src [K][N] fp32 (expert z) -> dst [N][K] bf16; optional sn[k] scale
template<bool SN>
__global__ __launch_bounds__(256) void convT_kernel(const float* __restrict__ src,
                                                    u16* __restrict__ dst, int K, int N,
                                                    const float* __restrict__ sn)
{
  const int z = blockIdx.z;
  const int n0 = blockIdx.x*64, k0 = blockIdx.y*64;
  src += (size_t)z*K*N; dst += (size_t)z*N*K;
  const float* snp = SN ? (sn + (size_t)z*HD + k0) : nullptr;
  __shared__ float tile[64][65];
  const int t = threadIdx.x;
  const int kr = t>>4, nc = t&15;
  #pragma unroll
  for (int i=0;i<4;i++){
    const int k = kr + 16*i;
    const float4 v = *(const float4*)(src + (size_t)(k0+k)*N + n0 + nc*4);
    tile[k][nc*4+0]=v.x; tile[k][nc*4+1]=v.y; tile[k][nc*4+2]=v.z; tile[k][nc*4+3]=v.w;
  }
  __syncthreads();
  const int nr = t>>3, kc = t&7;
  float sv[8];
  #pragma unroll
  for (int j=0;j<8;j++) sv[j] = SN ? snp[kc*8+j] : 1.0f;
  #pragma unroll
  for (int p=0;p<2;p++){
    const int n = nr + 32*p;
    unsigned d0 = pk2(tile[kc*8+0][n]*sv[0], tile[kc*8+1][n]*sv[1]);
    unsigned d1 = pk2(tile[kc*8+2][n]*sv[2], tile[kc*8+3][n]*sv[3]);
    unsigned d2 = pk2(tile[kc*8+4][n]*sv[4], tile[kc*8+5][n]*sv[5]);
    unsigned d3 = pk2(tile[kc*8+6][n]*sv[6], tile[kc*8+7][n]*sv[7]);
    *(uint4*)(dst + (size_t)(n0+n)*K + k0 + kc*8) = make_uint4(d0,d1,d2,d3);
  }
}

// ---- shared up, FUSED fp32-B transpose-convert + sn-fold (up3 template).
// BM=256, dual W1|W3 BN=64. 1-D XCD-localized grid. r applied in epilogue.
__global__ __launch_bounds__(256, 2) void up2f_kernel(
    const u16* __restrict__ xb, const float* __restrict__ W1b, const float* __restrict__ W3b,
    const float* __restrict__ snb, u16* __restrict__ Ob, const float* __restrict__ rvec)
{
  const int b = blockIdx.x;                 // 0..1535
  const int z = b & 7;
  const int r = b >> 3;                     // 0..191
  const int xt = r >> 2;                    // 0..47  (n-tile)
  const int yt = r & 3;                     // 0..3   (m-tile, innermost)
  const int m0 = yt * 256;
  const int n0 = xt * 64;
  const float* W1 = W1b + (size_t)z*HD*NF3;   // [1024k][3072n] fp32
  const float* W3 = W3b + (size_t)z*HD*NF3;
  const float* sn = snb + (size_t)z*HD;
  u16* O = Ob + (size_t)z*TK*NF3;

  __shared__ alignas(16) u16   Al[256*64];     // 32KB A bf16 [m][k] swz8
  __shared__ alignas(16) float Scr[2*64*64];   // 32KB fp32 scratch (W1 | W3)
  __shared__ alignas(16) u16   Bl[2*64*64];    // 16KB B bf16 [n][k] swz8 (W1 | W3)
  char* Alc = (char*)Al; char* Blc = (char*)Bl; char* Scc = (char*)Scr;

  const int tid = threadIdx.x, w = tid>>6, l = tid&63;
  const int wm = (w>>1)*128, wn = (w&1)*32;

  int aofs[8];
  #pragma unroll
  for (int p=0;p<8;p++){
    const int id = p*256 + tid;
    const int row = id>>3;
    const int chunk = (id&7) ^ (row&7);
    aofs[p] = (m0+row)*HD + chunk*8;
  }
  int bofs[8];
  #pragma unroll
  for (int p=0;p<8;p++){
    const int id = (p&3)*256 + tid;           // 0..1023 per mat
    const int k = id>>4, c = id&15;
    bofs[p] = k*NF3 + n0 + chunkperm(c, k)*4;
  }

  f32x4 acc1[8][2] = {}; f32x4 acc3[8][2] = {};

  constexpr int NT = HD/64;                   // 16
  for (int t=0; t<NT; ++t){
    #pragma unroll
    for (int p=0;p<8;p++) GLDS16(xb + aofs[p] + t*64, Alc + ((p*256+tid)<<4));
    #pragma unroll
    for (int p=0;p<4;p++) GLDS16(W1 + bofs[p] + (size_t)t*64*NF3, Scc + ((p*256+tid)<<4));
    #pragma unroll
    for (int p=4;p<8;p++) GLDS16(W3 + bofs[p] + (size_t)t*64*NF3, Scc + 16384 + (((p-4)*256+tid)<<4));
    __syncthreads();

    {
      const int nq = tid&15, kq = tid>>4;
      float sv[4];
      #pragma unroll
      for (int i=0;i<4;i++) sv[i] = sn[t*64 + kq*4 + i];
      #pragma unroll
      for (int m2=0;m2<2;m2++){
        const char* sc = Scc + m2*16384;
        char* bd = Blc + m2*8192;
        float4 v[4];
        #pragma unroll
        for (int i=0;i<4;i++){
          v[i] = *(const float4*)(sc + scrofs(kq*4+i, nq));
          v[i].x *= sv[i]; v[i].y *= sv[i]; v[i].z *= sv[i]; v[i].w *= sv[i];
        }
        #pragma unroll
        for (int j=0;j<4;j++){
          const int n = nq*4+j;
          uint2 wv;
          wv.x = pk2(v[0][j], v[1][j]);
          wv.y = pk2(v[2][j], v[3][j]);
          *(uint2*)(bd + n*128 + (((kq>>1)^(n&7))<<4) + ((kq&1)<<3)) = wv;
        }
      }
    }
    __syncthreads();

    #pragma unroll
    for (int kh=0;kh<2;kh++){
      bf16x8 af[8], b1[2], b3[2];
      #pragma unroll
      for (int mi=0;mi<8;mi++)
        af[mi] = *(const bf16x8*)(Alc + swz8(wm + mi*16 + (l&15), kh*4 + (l>>4)));
      #pragma unroll
      for (int ni=0;ni<2;ni++){
        b1[ni] = *(const bf16x8*)(Blc +        swz8(wn + ni*16 + (l&15), kh*4 + (l>>4)));
        b3[ni] = *(const bf16x8*)(Blc + 8192 + swz8(wn + ni*16 + (l&15), kh*4 + (l>>4)));
      }
      #pragma unroll
      for (int mi=0;mi<8;mi++){
        #pragma unroll
        for (int ni=0;ni<2;ni++){
          acc1[mi][ni] = __builtin_amdgcn_mfma_f32_16x16x32_bf16(af[mi], b1[ni], acc1[mi][ni], 0,0,0);
          acc3[mi][ni] = __builtin_amdgcn_mfma_f32_16x16x32_bf16(af[mi], b3[ni], acc3[mi][ni], 0,0,0);
        }
      }
    }
    __syncthreads();
  }

  #pragma unroll
  for (int mi=0;mi<8;mi++){
    #pragma unroll
    for (int ni=0;ni<2;ni++){
      #pragma unroll
      for (int r2=0;r2<4;r2++){
        const int row = wm + mi*16 + ((l>>4)<<2) + r2;
        const float rr = rvec[m0+row];
        const float v1 = rr*acc1[mi][ni][r2], v3 = rr*acc3[mi][ni][r2];
        const float h = v3 * v1 / (1.0f + expf(-v1));
        O[(size_t)(m0+row)*NF3 + n0 + wn + ni*16 + (l&15)] = f2b(h);
      }
    }
  }
}

// ---- shared down partial: Sbuf[e][t][h] = (H_e @ sw2t_e), 128x128, 1-D XCD grid ----
__global__ __launch_bounds__(256, 2) void sdown_kernel(
    const u16* __restrict__ Hb, const u16* __restrict__ W2t, float* __restrict__ Sbuf)
{
  const int b = blockIdx.x;                 // 0..511
  const int e = b & 7;
  const int r = b >> 3;                     // 0..63
  const int xt = r >> 3;                    // 0..7   (n-tile)
  const int yt = r & 7;                     // 0..7   (m-tile, innermost)
  const int m0 = yt * 128;
  const int n0 = xt * 128;
  const u16* A  = Hb  + (size_t)e*TK*NF3;
  const u16* W2 = W2t + (size_t)e*HD*NF3;

  __shared__ alignas(16) u16 Al[128*64];
  __shared__ alignas(16) u16 Bl[128*64];
  char* Alc = (char*)Al; char* Blc = (char*)Bl;

  const int tid = threadIdx.x, w = tid>>6, l = tid&63;
  const int wm = (w>>1)*64, wn = (w&1)*64;

  const u16 *asrc[4], *bsrc[4];
  #pragma unroll
  for (int p=0;p<4;p++){
    const int id = p*256 + tid;
    const int row = id>>3;
    const int chunk = (id&7)^(row&7);
    asrc[p] = A  + (size_t)(m0+row)*NF3 + chunk*8;
    bsrc[p] = W2 + (size_t)(n0+row)*NF3 + chunk*8;
  }

  f32x4 acc[4][4] = {};

  auto issue = [&](int ke){
    #pragma unroll
    for (int p=0;p<4;p++) GLDS16(asrc[p] + ke, Alc + ((p*256+tid)<<4));
    #pragma unroll
    for (int p=0;p<4;p++) GLDS16(bsrc[p] + ke, Blc + ((p*256+tid)<<4));
  };
  auto compute = [&](){
    #pragma unroll
    for (int kh=0;kh<2;kh++){
      bf16x8 af[4], bfr[4];
      #pragma unroll
      for (int mi=0;mi<4;mi++)
        af[mi]  = *(const bf16x8*)(Alc + swz8(wm + mi*16 + (l&15), kh*4 + (l>>4)));
      #pragma unroll
      for (int ni=0;ni<4;ni++)
        bfr[ni] = *(const bf16x8*)(Blc + swz8(wn + ni*16 + (l&15), kh*4 + (l>>4)));
      #pragma unroll
      for (int mi=0;mi<4;mi++){
        #pragma unroll
        for (int ni=0;ni<4;ni++)
          acc[mi][ni] = __builtin_amdgcn_mfma_f32_16x16x32_bf16(af[mi], bfr[ni], acc[mi][ni], 0,0,0);
      }
    }
  };

  constexpr int NT = NF3/64;                // 48
  for (int t=0; t<NT; ++t){
    issue(t*64);
    __syncthreads();
    compute();
    __syncthreads();
  }

  #pragma unroll
  for (int mi=0;mi<4;mi++){
    #pragma unroll
    for (int ni=0;ni<4;ni++){
      #pragma unroll
      for (int r2=0;r2<4;r2++){
        const int row = wm + mi*16 + ((l>>4)<<2) + r2;
        const int col = n0 + wn + ni*16 + (l&15);
        Sbuf[((size_t)e*TK + m0+row)*HD + col] = acc[mi][ni][r2];
      }
    }
  }
}

// ---- routed up, FUSED fp32-B transpose-convert via LDS scratch (BM=256) ----
__global__ __launch_bounds__(256, 2) void up3_kernel(
    const u16* __restrict__ xb, const float* __restrict__ W1b, const float* __restrict__ W3b,
    u16* __restrict__ Ob, const int* __restrict__ counts, const int* __restrict__ offsets,
    const int* __restrict__ tok_of)
{
  const int z  = blockIdx.z;
  const int m0 = blockIdx.y * 256;
  const int n0 = blockIdx.x * 64;
  const int Meff = counts[z];
  if (m0 >= Meff) return;
  const int off = offsets[z];
  const int* toks = tok_of + off;
  const float* W1 = W1b + (size_t)z*HD*NF2;
  const float* W3 = W3b + (size_t)z*HD*NF2;
  u16* O = Ob + (size_t)off*NF2;

  __shared__ alignas(16) u16   Al[256*64];
  __shared__ alignas(16) float Scr[2*64*64];
  __shared__ alignas(16) u16   Bl[2*64*64];
  char* Alc = (char*)Al; char* Blc = (char*)Bl; char* Scc = (char*)Scr;

  const int tid = threadIdx.x, w = tid>>6, l = tid&63;
  const int wm = (w>>1)*128, wn = (w&1)*32;

  int aofs[8];
  #pragma unroll
  for (int p=0;p<8;p++){
    const int id = p*256 + tid;
    const int row = id>>3;
    const int chunk = (id&7) ^ (row&7);
    int mg = m0 + row;
    mg = toks[(mg < Meff) ? mg : (Meff-1)];
    aofs[p] = mg*HD + chunk*8;
  }
  int bofs[8];
  #pragma unroll
  for (int p=0;p<8;p++){
    const int id = (p&3)*256 + tid;
    const int k = id>>4, c = id&15;
    bofs[p] = k*NF2 + n0 + chunkperm(c, k)*4;
  }

  f32x4 acc1[8][2] = {}; f32x4 acc3[8][2] = {};

  constexpr int NT = HD/64;
  for (int t=0; t<NT; ++t){
    #pragma unroll
    for (int p=0;p<8;p++) GLDS16(xb + aofs[p] + t*64, Alc + ((p*256+tid)<<4));
    #pragma unroll
    for (int p=0;p<4;p++) GLDS16(W1 + bofs[p] + (size_t)t*64*NF2, Scc + ((p*256+tid)<<4));
    #pragma unroll
    for (int p=4;p<8;p++) GLDS16(W3 + bofs[p] + (size_t)t*64*NF2, Scc + 16384 + (((p-4)*256+tid)<<4));
    __syncthreads();

    {
      const int nq = tid&15, kq = tid>>4;
      #pragma unroll
      for (int m2=0;m2<2;m2++){
        const char* sc = Scc + m2*16384;
        char* bd = Blc + m2*8192;
        float4 v[4];
        #pragma unroll
        for (int i=0;i<4;i++) v[i] = *(const float4*)(sc + scrofs(kq*4+i, nq));
        #pragma unroll
        for (int j=0;j<4;j++){
          const int n = nq*4+j;
          uint2 wv;
          wv.x = pk2(v[0][j], v[1][j]);
          wv.y = pk2(v[2][j], v[3][j]);
          *(uint2*)(bd + n*128 + (((kq>>1)^(n&7))<<4) + ((kq&1)<<3)) = wv;
        }
      }
    }
    __syncthreads();

    #pragma unroll
    for (int kh=0;kh<2;kh++){
      bf16x8 af[8], b1[2], b3[2];
      #pragma unroll
      for (int mi=0;mi<8;mi++)
        af[mi] = *(const bf16x8*)(Alc + swz8(wm + mi*16 + (l&15), kh*4 + (l>>4)));
      #pragma unroll
      for (int ni=0;ni<2;ni++){
        b1[ni] = *(const bf16x8*)(Blc +        swz8(wn + ni*16 + (l&15), kh*4 + (l>>4)));
        b3[ni] = *(const bf16x8*)(Blc + 8192 + swz8(wn + ni*16 + (l&15), kh*4 + (l>>4)));
      }
      #pragma unroll
      for (int mi=0;mi<8;mi++){
        #pragma unroll
        for (int ni=0;ni<2;ni++){
          acc1[mi][ni] = __builtin_amdgcn_mfma_f32_16x16x32_bf16(af[mi], b1[ni], acc1[mi][ni], 0,0,0);
          acc3[mi][ni] = __builtin_amdgcn_mfma_f32_16x16x32_bf16(af[mi], b3[ni], acc3[mi][ni], 0,0,0);
        }
      }
    }
    __syncthreads();
  }

  #pragma unroll
  for (int mi=0;mi<8;mi++){
    #pragma unroll
    for (int ni=0;ni<2;ni++){
      #pragma unroll
      for (int r2=0;r2<4;r2++){
        const int row = wm + mi*16 + ((l>>4)<<2) + r2;
        const int mg  = m0 + row;
        if (mg >= Meff) continue;
        const float v1 = acc1[mi][ni][r2], v3 = acc3[mi][ni][r2];
        const float h = v3 * v1 / (1.0f + expf(-v1));
        O[(size_t)mg*NF2 + n0 + wn + ni*16 + (l&15)] = f2b(h);
      }
    }
  }
}

// ---- routed down, FUSED fp32-B transpose-convert: Ebuf[slot][h] = G @ rw2_e ----
__global__ __launch_bounds__(256, 2) void rdown_f_kernel(
    const u16* __restrict__ Gb, const float* __restrict__ W2b, float* __restrict__ Ebuf,
    const int* __restrict__ counts, const int* __restrict__ offsets)
{
  const int z  = blockIdx.z;
  const int m0 = blockIdx.y * 128;
  const int n0 = blockIdx.x * 64;
  const int Meff = counts[z];
  if (m0 >= Meff) return;
  const int off = offsets[z];
  const u16* A = Gb + (size_t)off*NF2;
  const float* W2 = W2b + (size_t)z*NF2*HD;

  __shared__ alignas(16) u16   Al[128*64];
  __shared__ alignas(16) float Scr[64*64];
  __shared__ alignas(16) u16   Bl[64*64];
  char* Alc = (char*)Al; char* Blc = (char*)Bl; char* Scc = (char*)Scr;

  const int tid = threadIdx.x, w = tid>>6, l = tid&63;
  const int wm = (w>>1)*64, wn = (w&1)*32;

  int aofs[4];
  #pragma unroll
  for (int p=0;p<4;p++){
    const int id = p*256 + tid;
    const int row = id>>3;
    const int chunk = (id&7) ^ (row&7);
    int mg = m0 + row; if (mg >= Meff) mg = Meff-1;
    aofs[p] = mg*NF2 + chunk*8;
  }
  int bofs[4];
  #pragma unroll
  for (int p=0;p<4;p++){
    const int id = p*256 + tid;
    const int k = id>>4, c = id&15;
    bofs[p] = k*HD + n0 + chunkperm(c, k)*4;
  }

  f32x4 acc[4][2] = {};

  constexpr int NT = NF2/64;
  for (int t=0; t<NT; ++t){
    #pragma unroll
    for (int p=0;p<4;p++) GLDS16(A + aofs[p] + t*64, Alc + ((p*256+tid)<<4));
    #pragma unroll
    for (int p=0;p<4;p++) GLDS16(W2 + bofs[p] + (size_t)t*64*HD, Scc + ((p*256+tid)<<4));
    __syncthreads();

    {
      const int nq = tid&15, kq = tid>>4;
      float4 v[4];
      #pragma unroll
      for (int i=0;i<4;i++) v[i] = *(const float4*)(Scc + scrofs(kq*4+i, nq));
      #pragma unroll
      for (int j=0;j<4;j++){
        const int n = nq*4+j;
        uint2 wv;
        wv.x = pk2(v[0][j], v[1][j]);
        wv.y = pk2(v[2][j], v[3][j]);
        *(uint2*)(Blc + n*128 + (((kq>>1)^(n&7))<<4) + ((kq&1)<<3)) = wv;
      }
    }
    __syncthreads();

    #pragma unroll
    for (int kh=0;kh<2;kh++){
      bf16x8 af[4], bfr[2];
      #pragma unroll
      for (int mi=0;mi<4;mi++)
        af[mi]  = *(const bf16x8*)(Alc + swz8(wm + mi*16 + (l&15), kh*4 + (l>>4)));
      #pragma unroll
      for (int ni=0;ni<2;ni++)
        bfr[ni] = *(const bf16x8*)(Blc + swz8(wn + ni*16 + (l&15), kh*4 + (l>>4)));
      #pragma unroll
      for (int mi=0;mi<4;mi++){
        #pragma unroll
        for (int ni=0;ni<2;ni++)
          acc[mi][ni] = __builtin_amdgcn_mfma_f32_16x16x32_bf16(af[mi], bfr[ni], acc[mi][ni], 0,0,0);
      }
    }
    __syncthreads();
  }

  #pragma unroll
  for (int mi=0;mi<4;mi++){
    #pragma unroll
    for (int ni=0;ni<2;ni++){
      #pragma unroll
      for (int r2=0;r2<4;r2++){
        const int row = wm + mi*16 + ((l>>4)<<2) + r2;
        const int mg  = m0 + row;
        if (mg >= Meff) continue;
        const int col = n0 + wn + ni*16 + (l&15);
        Ebuf[((size_t)off+mg)*HD + col] = acc[mi][ni][r2];
      }
    }
  }
}

// ---- combine: out = x + 0.125*sum_s Sbuf + sum_k wts*Ebuf[slot] ----
__global__ __launch_bounds__(256) void combine_kernel(
    const float* __restrict__ x, const float* __restrict__ Sbuf,
    const float* __restrict__ Ebuf, const float* __restrict__ wts,
    const int* __restrict__ slot_of, float* __restrict__ out)
{
  const int t = blockIdx.x, tid = threadIdx.x;
  float4 o = ((const float4*)(x + (size_t)t*HD))[tid];
  float4 s = make_float4(0.f,0.f,0.f,0.f);
  #pragma unroll
  for (int e=0;e<NSH;e++){
    const float4 v = ((const float4*)(Sbuf + ((size_t)e*TK + t)*HD))[tid];
    s.x+=v.x; s.y+=v.y; s.z+=v.z; s.w+=v.w;
  }
  o.x += 0.125f*s.x; o.y += 0.125f*s.y; o.z += 0.125f*s.z; o.w += 0.125f*s.w;
  #pragma unroll
  for (int k=0;k<KSEL;k++){
    const float wgt = wts[t*KSEL+k];
    const int slot  = slot_of[t*KSEL+k];
    const float4 v = ((const float4*)(Ebuf + (size_t)slot*HD))[tid];
    o.x += wgt*v.x; o.y += wgt*v.y; o.z += wgt*v.z; o.w += wgt*v.w;
  }
  ((float4*)(out + (size_t)t*HD))[tid] = o;
}

// ---- fallback kernels (reg-staged fp32 B) for small-ws path ----

template<int NDIM, bool ROUTED>
__global__ __launch_bounds__(256, 2) void up_kernel(
    const u16* __restrict__ Ab, const float* __restrict__ W1b, const float* __restrict__ W3b,
    u16* __restrict__ Ob, const int* __restrict__ counts, const int* __restrict__ offsets,
    const int* __restrict__ tok_of)
{
  const int z  = blockIdx.z;
  const int m0 = blockIdx.y * 128;
  const int n0 = blockIdx.x * 64;

  int Meff; const u16* A; const float *W1, *W3; u16* O; const int* toks = nullptr;
  if (ROUTED){
    Meff = counts[z];
    if (m0 >= Meff) return;
    const int off = offsets[z];
    toks = tok_of + off; A = Ab;
    W1 = W1b + (size_t)z*HD*NDIM; W3 = W3b + (size_t)z*HD*NDIM;
    O  = Ob  + (size_t)off*NDIM;
  } else {
    Meff = TK;
    A  = Ab  + (size_t)z*TK*HD;
    W1 = W1b + (size_t)z*HD*NDIM; W3 = W3b + (size_t)z*HD*NDIM;
    O  = Ob  + (size_t)z*TK*NDIM;
  }

  __shared__ alignas(16) u16 Al[128*64];
  __shared__ alignas(16) u16 Bl[128*64];
  char* Alc = (char*)Al; char* Blc = (char*)Bl;

  const int tid = threadIdx.x, w = tid>>6, l = tid&63;
  const int wm = (w>>1)*64, wn = (w&1)*32;

  const u16* asrc[4];
  #pragma unroll
  for (int p=0;p<4;p++){
    const int id  = p*256 + tid;
    const int row = id>>3;
    const int chunk = (id&7) ^ (row&7);
    int mg = m0 + row;
    if (ROUTED) mg = toks[(mg < Meff) ? mg : (Meff-1)];
    asrc[p] = A + (size_t)mg*HD + chunk*8;
  }
  const int br = tid&127, bhalf = tid>>7;
  const float* bsrc0 = ((br<64) ? W1 : W3) + (size_t)bhalf*32*NDIM + (n0 + (br&63));

  f32x4 acc1[4][2] = {}; f32x4 acc3[4][2] = {};

  auto issueA = [&](int ke){
    #pragma unroll
    for (int p=0;p<4;p++) GLDS16(asrc[p] + ke, Alc + ((p*256+tid)<<4));
  };
  auto loadB = [&](float* f, int t){
    const float* s_ = bsrc0 + (size_t)t*64*NDIM;
    #pragma unroll
    for (int i=0;i<32;i++) f[i] = s_[(size_t)i*NDIM];
  };
  auto writeB = [&](const float* f){
    #pragma unroll
    for (int j=0;j<4;j++){
      const uint4 v = make_uint4(pk2(f[j*8+0],f[j*8+1]), pk2(f[j*8+2],f[j*8+3]),
                                 pk2(f[j*8+4],f[j*8+5]), pk2(f[j*8+6],f[j*8+7]));
      *(uint4*)(Blc + swz8(br, bhalf*4+j)) = v;
    }
  };
  auto compute = [&](){
    #pragma unroll
    for (int kh=0;kh<2;kh++){
      bf16x8 af[4], b1[2], b3[2];
      #pragma unroll
      for (int mi=0;mi<4;mi++)
        af[mi] = *(const bf16x8*)(Alc + swz8(wm + mi*16 + (l&15), kh*4 + (l>>4)));
      #pragma unroll
      for (int ni=0;ni<2;ni++){
        b1[ni] = *(const bf16x8*)(Blc + swz8(     wn + ni*16 + (l&15), kh*4 + (l>>4)));
        b3[ni] = *(const bf16x8*)(Blc + swz8(64 + wn + ni*16 + (l&15), kh*4 + (l>>4)));
      }
      #pragma unroll
      for (int mi=0;mi<4;mi++){
        #pragma unroll
        for (int ni=0;ni<2;ni++){
          acc1[mi][ni] = __builtin_amdgcn_mfma_f32_16x16x32_bf16(af[mi], b1[ni], acc1[mi][ni], 0,0,0);
          acc3[mi][ni] = __builtin_amdgcn_mfma_f32_16x16x32_bf16(af[mi], b3[ni], acc3[mi][ni], 0,0,0);
        }
      }
    }
  };

  float fb[32];
  loadB(fb, 0);
  constexpr int NT = HD/64;
  for (int t=0; t<NT; ++t){
    writeB(fb);
    issueA(t*64);
    __syncthreads();
    if (t+1 < NT) loadB(fb, t+1);
    compute();
    __syncthreads();
  }

  #pragma unroll
  for (int mi=0;mi<4;mi++){
    #pragma unroll
    for (int ni=0;ni<2;ni++){
      #pragma unroll
      for (int r2=0;r2<4;r2++){
        const int row = wm + mi*16 + ((l>>4)<<2) + r2;
        const int mg  = m0 + row;
        if (ROUTED && mg >= Meff) continue;
        const float v1 = acc1[mi][ni][r2], v3 = acc3[mi][ni][r2];
        const float h = v3 * v1 / (1.0f + expf(-v1));
        O[(size_t)mg*NDIM + n0 + wn + ni*16 + (l&15)] = f2b(h);
      }
    }
  }
}

template<bool ROUTED>
__global__ __launch_bounds__(256, 2) void down_kernel(
    const u16* __restrict__ Ab, const float* __restrict__ W2b, float* __restrict__ out,
    const int* __restrict__ counts, const int* __restrict__ offsets,
    const int* __restrict__ tok_of, const float* __restrict__ wt_of)
{
  const int z  = blockIdx.z;
  const int m0 = blockIdx.y * 128;
  const int n0 = blockIdx.x * 128;
  constexpr int KT  = ROUTED ? NF2 : NF3;
  constexpr int KCH = ROUTED ? 512 : 1024;

  int Meff = TK, off = 0, e, kb;
  const u16* A; const float* W2;
  if (ROUTED){
    e = z>>2; kb = (z&3)*KCH;
    Meff = counts[e];
    if (m0 >= Meff) return;
    off = offsets[e];
    A  = Ab  + (size_t)off*NF2;
    W2 = W2b + (size_t)e*NF2*HD;
  } else {
    e = z/3; kb = (z - e*3)*KCH;
    A  = Ab  + (size_t)e*TK*NF3;
    W2 = W2b + (size_t)e*NF3*HD;
  }

  __shared__ alignas(16) u16 Al[128*64];
  __shared__ alignas(16) u16 Bl[128*64];
  char* Alc = (char*)Al; char* Blc = (char*)Bl;

  const int tid = threadIdx.x, w = tid>>6, l = tid&63;
  const int wm = (w>>1)*64, wn = (w&1)*64;

  const u16* asrc[4];
  #pragma unroll
  for (int p=0;p<4;p++){
    const int id  = p*256 + tid;
    const int row = id>>3;
    const int chunk = (id&7) ^ (row&7);
    int mg = m0 + row;
    if (ROUTED && mg >= Meff) mg = Meff-1;
    asrc[p] = A + (size_t)mg*KT + kb + chunk*8;
  }
  const int br = tid&127, bhalf = tid>>7;
  const float* bsrc0 = W2 + (size_t)(bhalf*32 + kb)*HD + (n0 + br);

  f32x4 acc[4][4] = {};

  auto issueA = [&](int ke){
    #pragma unroll
    for (int p=0;p<4;p++) GLDS16(asrc[p] + ke, Alc + ((p*256+tid)<<4));
  };
  auto loadB = [&](float* f, int t){
    const float* s_ = bsrc0 + (size_t)t*64*HD;
    #pragma unroll
    for (int i=0;i<32;i++) f[i] = s_[(size_t)i*HD];
  };
  auto writeB = [&](const float* f){
    #pragma unroll
    for (int j=0;j<4;j++){
      const uint4 v = make_uint4(pk2(f[j*8+0],f[j*8+1]), pk2(f[j*8+2],f[j*8+3]),
                                 pk2(f[j*8+4],f[j*8+5]), pk2(f[j*8+6],f[j*8+7]));
      *(uint4*)(Blc + swz8(br, bhalf*4+j)) = v;
    }
  };
  auto compute = [&](){
    #pragma unroll
    for (int kh=0;kh<2;kh++){
      bf16x8 af[4], bfr[4];
      #pragma unroll
      for (int mi=0;mi<4;mi++)
        af[mi]  = *(const bf16x8*)(Alc + swz8(wm + mi*16 + (l&15), kh*4 + (l>>4)));
      #pragma unroll
      for (int ni=0;ni<4;ni++)
        bfr[ni] = *(const bf16x8*)(Blc + swz8(wn + ni*16 + (l&15), kh*4 + (l>>4)));
      #pragma unroll
      for (int mi=0;mi<4;mi++){
        #pragma unroll
        for (int ni=0;ni<4;ni++)
          acc[mi][ni] = __builtin_amdgcn_mfma_f32_16x16x32_bf16(af[mi], bfr[ni], acc[mi][ni], 0,0,0);
      }
    }
  };

  float fb[32];
  loadB(fb, 0);
  constexpr int NT = KCH/64;
  for (int t=0; t<NT; ++t){
    writeB(fb);
    issueA(t*64);
    __syncthreads();
    if (t+1 < NT) loadB(fb, t+1);
    compute();
    __syncthreads();
  }

  #pragma unroll
  for (int mi=0;mi<4;mi++){
    #pragma unroll
    for (int ni=0;ni<4;ni++){
      #pragma unroll
      for (int r2=0;r2<4;r2++){
        const int row = wm + mi*16 + ((l>>4)<<2) + r2;
        const int mg  = m0 + row;
        const int col = n0 + wn + ni*16 + (l&15);
        if (ROUTED){
          if (mg >= Meff) continue;
          const int slot = off + mg;
          atomicAdd(&out[(size_t)tok_of[slot]*HD + col], wt_of[slot]*acc[mi][ni][r2]);
        } else {
          atomicAdd(&out[(size_t)mg*HD + col], 0.125f*acc[mi][ni][r2]);
        }
      }
    }
  }
}

// ---------------- launch ----------------

extern "C" void kernel_launch(void* const* d_in, const int* in_sizes, int n_in,
                              void* d_out, int out_size, void* d_ws, size_t ws_size,
                              hipStream_t stream)
{
  const float* x   = (const float*)d_in[0];
  const float* sn  = (const float*)d_in[1];
  const float* sw1 = (const float*)d_in[2];
  const float* sw2 = (const float*)d_in[3];
  const float* sw3 = (const float*)d_in[4];
  const float* rw1 = (const float*)d_in[5];
  const float* rw2 = (const float*)d_in[6];
  const float* rw3 = (const float*)d_in[7];
  const float* rd  = (const float*)d_in[8];
  const float* ru  = (const float*)d_in[9];
  float* out = (float*)d_out;

  char* ws = (char*)d_ws;
  u16* xb    = (u16*)(ws);                               // 2 MB
  u16* xnb   = (u16*)(ws + ((size_t)2<<20));             // 16 MB (fallback only)
  u16* Hbuf  = (u16*)(ws + ((size_t)18<<20));            // 48 MB
  u16* Gbuf  = (u16*)(ws + ((size_t)66<<20));            // 16 MB
  char* aux  = ws + ((size_t)82<<20);
  int*   sel    = (int*)(aux);
  float* wts    = (float*)(aux + 16384);
  int*   counts = (int*)(aux + 32768);
  int*   offs   = (int*)(aux + 33024);
  int*   curs   = (int*)(aux + 33280);
  int*   tok_of = (int*)(aux + 34816);
  float* wt_of  = (float*)(aux + 34816 + 16384);
  int*   slot_of= (int*)(aux + 34816 + 32768);
  float* rvec   = (float*)(aux + 34816 + 49152);
  const size_t WSLICE   = (size_t)NSH*NF3*HD*2;          // 50,331,648
  const size_t WBASE    = (size_t)84<<20;
  const size_t SBUF_OFF = WBASE + 3*WSLICE;              // 239,075,328
  const size_t SBUF_SZ  = (size_t)NSH*TK*HD*4;           // 33,554,432
  const size_t EBUF_OFF = SBUF_OFF + SBUF_SZ;
  const size_t EBUF_SZ  = (size_t)TK*KSEL*HD*4;          // 16,777,216
  const bool  full = ws_size >= EBUF_OFF + EBUF_SZ;      // ~290 MB
  u16* sw2t = (u16*)(ws + WBASE + 2*WSLICE);
  float* Sbuf = (float*)(ws + SBUF_OFF);
  float* Ebuf = (float*)(ws + EBUF_OFF);

  hipLaunchKernelGGL(init_kernel, dim3(1), dim3(64), 0, stream, counts, curs);
  hipLaunchKernelGGL(rms_kernel, dim3(TK), dim3(256), 0, stream, x, sn, xb, xnb, out, rvec,
                     full ? 0 : 1);
  hipLaunchKernelGGL(router_kernel, dim3(TK), dim3(64), 0, stream, x, rd, ru, sel, wts, counts);
  hipLaunchKernelGGL(scan_loss_kernel, dim3(1), dim3(64), 0, stream, counts, offs,
                     out + (size_t)TK*HD);
  hipLaunchKernelGGL(scatter_kernel, dim3(16), dim3(256), 0, stream, sel, wts, offs, curs,
                     tok_of, wt_of, slot_of);

  if (full){
    // sw2 -> bf16 [n][k] (re-read x8 in sdown, conversion pays for itself)
    hipLaunchKernelGGL((convT_kernel<false>), dim3(HD/64, NF3/64, NSH), dim3(256), 0, stream,
                       sw2, sw2t, NF3, HD, nullptr);
    // shared up: FUSED fp32 staging + sn fold (no convT for sw1/sw3)
    hipLaunchKernelGGL(up2f_kernel, dim3((NF3/64)*(TK/256)*NSH), dim3(256), 0, stream,
                       xb, sw1, sw3, sn, Hbuf, rvec);
    // routed up: fused fp32-B transpose-convert, BM=256
    hipLaunchKernelGGL(up3_kernel, dim3(NF2/64, 2, NEX), dim3(256), 0, stream,
                       xb, rw1, rw3, Gbuf, counts, offs, tok_of);
    // shared down partial (128x128, 1-D XCD-localized grid)
    hipLaunchKernelGGL(sdown_kernel, dim3((HD/128)*(TK/128)*NSH), dim3(256), 0, stream,
                       Hbuf, sw2t, Sbuf);
    // routed down: fused fp32-B transpose-convert, no atomics
    hipLaunchKernelGGL(rdown_f_kernel, dim3(HD/64, 2, NEX), dim3(256), 0, stream,
                       Gbuf, rw2, Ebuf, counts, offs);
    // final combine
    hipLaunchKernelGGL(combine_kernel, dim3(TK), dim3(256), 0, stream,
                       x, Sbuf, Ebuf, wts, slot_of, out);
  } else {
    hipLaunchKernelGGL((up_kernel<NF3, false>), dim3(NF3/64, TK/128, NSH), dim3(256), 0,
                       stream, xnb, sw1, sw3, Hbuf, nullptr, nullptr, nullptr);
    hipLaunchKernelGGL((up_kernel<NF2, true>), dim3(NF2/64, TK/128, NEX), dim3(256), 0,
                       stream, xb, rw1, rw3, Gbuf, counts, offs, tok_of);
    hipLaunchKernelGGL((down_kernel<false>), dim3(HD/128, TK/128, NSH*3), dim3(256), 0, stream,
                       Hbuf, sw2, out, nullptr, nullptr, nullptr, nullptr);
    hipLaunchKernelGGL((down_kernel<true>), dim3(HD/128, TK/128, NEX*4), dim3(256), 0, stream,
                       Gbuf, rw2, out, counts, offs, tok_of, wt_of);
  }
}

// Round 13
// 597.831 us; speedup vs baseline: 1.0459x; 1.0459x over previous
//
#include <hip/hip_runtime.h>
#include <hip/hip_bf16.h>
#include <math.h>

// Problem constants
#define TK 1024      // tokens
#define HD 1024      // hidden
#define NF3 3072     // shared ffn dim
#define NF2 2048     // routed ffn dim
#define NSH 8        // shared experts
#define NEX 32       // routed experts
#define KSEL 4       // top-k
#define RRK 64       // router rank

typedef short bf16x8 __attribute__((ext_vector_type(8)));
typedef float f32x4 __attribute__((ext_vector_type(4)));
typedef unsigned short u16;

__device__ __forceinline__ u16 f2b(float f){
  union{float f; unsigned u;} c; c.f=f;
  unsigned r = c.u + 0x7FFFu + ((c.u>>16)&1u);
  return (u16)(r>>16);
}

__device__ __forceinline__ unsigned pk2(float a, float b){
  __hip_bfloat162 h = __float22bfloat162_rn(float2{a, b});
  union{__hip_bfloat162 h; unsigned u;} c; c.h = h; return c.u;
}

// XOR swizzle for [row][64k] bf16 LDS tiles (128B rows, 8 chunks of 16B)
__device__ __forceinline__ int swz8(int row, int c){
  return row*128 + ((c ^ (row&7))<<4);
}
// B-LDS swizzle for fused-transpose kernels: slot = c ^ ((row>>1)&7).
// Write side (uint2 per lane, n=4*nq+j) spreads 64 lanes over 8 slots x 2 halves
// (4/bank = floor) instead of 8-way with (row&7).
__device__ __forceinline__ int bswz(int row, int c){
  return row*128 + ((c ^ ((row>>1)&7))<<4);
}

// scratch fp32 [64k][64n] tile helpers (involutive chunk perm)
__device__ __forceinline__ int scrofs(int k, int nq){
  return k*256 + (((nq&8) | ((nq&7)^(k&7)))<<4);
}
__device__ __forceinline__ int chunkperm(int c, int k){
  return (c&8) | ((c&7)^(k&7));
}

#define GLDS16(gptr, lptr) \
  __builtin_amdgcn_global_load_lds((const __attribute__((address_space(1))) unsigned*)(gptr), \
                                   (__attribute__((address_space(3))) unsigned*)(lptr), 16, 0, 0)

// ---------------- small kernels ----------------

__global__ void init_kernel(int* counts, int* cursors){
  int i = threadIdx.x;
  if (i < NEX){ counts[i]=0; cursors[i]=0; }
}

// compute r per token; write xb = bf16(x), rvec[t]=r. If XNB: also xnb + out=x (fallback).
__global__ void rms_kernel(const float* __restrict__ x, const float* __restrict__ sn,
                           u16* __restrict__ xb, u16* __restrict__ xnb,
                           float* __restrict__ out, float* __restrict__ rvec, int writeXnb)
{
  const int t = blockIdx.x, tid = threadIdx.x;
  const float4 v = ((const float4*)(x + (size_t)t*HD))[tid];
  float ss = v.x*v.x + v.y*v.y + v.z*v.z + v.w*v.w;
  #pragma unroll
  for (int m=32;m>=1;m>>=1) ss += __shfl_xor(ss, m);
  __shared__ float red[4];
  if ((tid&63)==0) red[tid>>6]=ss;
  __syncthreads();
  const float r = rsqrtf((red[0]+red[1]+red[2]+red[3])*(1.0f/HD) + 1e-6f);
  if (tid==0) rvec[t] = r;
  ushort4 o; o.x=f2b(v.x); o.y=f2b(v.y); o.z=f2b(v.z); o.w=f2b(v.w);
  ((ushort4*)(xb + (size_t)t*HD))[tid] = o;
  if (writeXnb){
    ((float4*)(out + (size_t)t*HD))[tid] = v;
    #pragma unroll
    for (int s=0;s<NSH;s++){
      const float4 g = ((const float4*)(sn + (size_t)s*HD))[tid];
      ushort4 q;
      q.x=f2b(v.x*r*g.x); q.y=f2b(v.y*r*g.y); q.z=f2b(v.z*r*g.z); q.w=f2b(v.w*r*g.w);
      ((ushort4*)(xnb + ((size_t)s*TK + t)*HD))[tid] = q;
    }
  }
}

__global__ void router_kernel(const float* __restrict__ x, const float* __restrict__ rd,
                              const float* __restrict__ ru,
                              int* __restrict__ sel, float* __restrict__ wts,
                              int* __restrict__ counts)
{
  const int t = blockIdx.x, l = threadIdx.x;
  __shared__ float xl[HD];
  __shared__ float xr[RRK];
  __shared__ float lg[NEX];
  const float* xrow = x + (size_t)t*HD;
  for (int i=l;i<HD;i+=64) xl[i]=xrow[i];
  __syncthreads();
  float acc=0.f;
  for (int h=0;h<HD;h++) acc += xl[h]*rd[h*RRK + l];
  xr[l]=acc;
  __syncthreads();
  if (l < NEX){
    float a=0.f;
    for (int r=0;r<RRK;r++) a += xr[r]*ru[r*NEX + l];
    lg[l]=a;
  }
  __syncthreads();
  if (l==0){
    int   sk[KSEL]; float val[KSEL]; unsigned used=0;
    for (int k=0;k<KSEL;k++){
      float best=-1e30f; int bi=0;
      for (int e=0;e<NEX;e++){
        if (used & (1u<<e)) continue;
        if (lg[e] > best){ best=lg[e]; bi=e; }
      }
      used |= (1u<<bi); sk[k]=bi; val[k]=best;
    }
    const float m = val[0];
    float w[KSEL], s=0.f;
    for (int k=0;k<KSEL;k++){ w[k]=expf(val[k]-m); s+=w[k]; }
    for (int k=0;k<KSEL;k++){
      sel[t*KSEL+k]=sk[k]; wts[t*KSEL+k]=w[k]/s;
      atomicAdd(&counts[sk[k]], 1);
    }
  }
}

__global__ void scan_loss_kernel(const int* __restrict__ counts, int* __restrict__ offsets,
                                 float* __restrict__ out_loss)
{
  if (threadIdx.x==0){
    int off=0; float var=0.f;
    for (int e=0;e<NEX;e++){
      offsets[e]=off; off+=counts[e];
      float d = (float)counts[e] - 128.0f;
      var += d*d;
    }
    out_loss[0] = var * (1.0f/31.0f);
  }
}

__global__ void scatter_kernel(const int* __restrict__ sel, const float* __restrict__ wts,
                               const int* __restrict__ offsets, int* __restrict__ cursors,
                               int* __restrict__ tok_of, float* __restrict__ wt_of,
                               int* __restrict__ slot_of)
{
  const int id = blockIdx.x*256 + threadIdx.x;
  const int e = sel[id];
  const int pos = atomicAdd(&cursors[e], 1);
  const int slot = offsets[e] + pos;
  tok_of[slot] = id >> 2;
  wt_of[slot]  = wts[id];
  slot_of[id]  = slot;
}

// transpose-convert: src [K][N] fp32 (expert z) -> dst [N][K] bf16; optional sn[k] scale
template<bool SN>
__global__ __launch_bounds__(256) void convT_kernel(const float* __restrict__ src,
                                                    u16* __restrict__ dst, int K, int N,
                                                    const float* __restrict__ sn)
{
  const int z = blockIdx.z;
  const int n0 = blockIdx.x*64, k0 = blockIdx.y*64;
  src += (size_t)z*K*N; dst += (size_t)z*N*K;
  const float* snp = SN ? (sn + (size_t)z*HD + k0) : nullptr;
  __shared__ float tile[64][65];
  const int t = threadIdx.x;
  const int kr = t>>4, nc = t&15;
  #pragma unroll
  for (int i=0;i<4;i++){
    const int k = kr + 16*i;
    const float4 v = *(const float4*)(src + (size_t)(k0+k)*N + n0 + nc*4);
    tile[k][nc*4+0]=v.x; tile[k][nc*4+1]=v.y; tile[k][nc*4+2]=v.z; tile[k][nc*4+3]=v.w;
  }
  __syncthreads();
  const int nr = t>>3, kc = t&7;
  float sv[8];
  #pragma unroll
  for (int j=0;j<8;j++) sv[j] = SN ? snp[kc*8+j] : 1.0f;
  #pragma unroll
  for (int p=0;p<2;p++){
    const int n = nr + 32*p;
    unsigned d0 = pk2(tile[kc*8+0][n]*sv[0], tile[kc*8+1][n]*sv[1]);
    unsigned d1 = pk2(tile[kc*8+2][n]*sv[2], tile[kc*8+3][n]*sv[3]);
    unsigned d2 = pk2(tile[kc*8+4][n]*sv[4], tile[kc*8+5][n]*sv[5]);
    unsigned d3 = pk2(tile[kc*8+6][n]*sv[6], tile[kc*8+7][n]*sv[7]);
    *(uint4*)(dst + (size_t)(n0+n)*K + k0 + kc*8) = make_uint4(d0,d1,d2,d3);
  }
}

// ---- shared up: BM=256, dual-B 64 (W1|W3), dual gload_lds, 2-barrier loop.
// 1-D XCD-localized grid: z=bid&7, y innermost. r applied in epilogue.
__global__ __launch_bounds__(256, 2) void up2_kernel(
    const u16* __restrict__ xb, const u16* __restrict__ W1t, const u16* __restrict__ W3t,
    u16* __restrict__ Ob, const float* __restrict__ rvec)
{
  const int b = blockIdx.x;                 // 0..1535
  const int z = b & 7;
  const int r = b >> 3;                     // 0..191
  const int xt = r >> 2;                    // 0..47  (n-tile)
  const int yt = r & 3;                     // 0..3   (m-tile, innermost)
  const int m0 = yt * 256;
  const int n0 = xt * 64;
  const u16* W1 = W1t + (size_t)z*NF3*HD;
  const u16* W3 = W3t + (size_t)z*NF3*HD;
  u16* O = Ob + (size_t)z*TK*NF3;

  __shared__ alignas(16) u16 Al[256*64];    // 32KB
  __shared__ alignas(16) u16 Bl[128*64];    // 16KB
  char* Alc = (char*)Al; char* Blc = (char*)Bl;

  const int tid = threadIdx.x, w = tid>>6, l = tid&63;
  const int wm = (w>>1)*128, wn = (w&1)*32;

  const u16 *asrc[8], *bsrc[4];
  #pragma unroll
  for (int p=0;p<8;p++){
    const int id = p*256 + tid;
    const int row = id>>3;
    const int chunk = (id&7) ^ (row&7);
    asrc[p] = xb + (size_t)(m0+row)*HD + chunk*8;
  }
  #pragma unroll
  for (int p=0;p<4;p++){
    const int id = p*256 + tid;
    const int row = id>>3;
    const int chunk = (id&7) ^ (row&7);
    bsrc[p] = ((row<64) ? (W1 + (size_t)(n0+row)*HD) : (W3 + (size_t)(n0+row-64)*HD)) + chunk*8;
  }

  f32x4 acc1[8][2] = {}; f32x4 acc3[8][2] = {};

  auto issue = [&](int ke){
    #pragma unroll
    for (int p=0;p<8;p++) GLDS16(asrc[p] + ke, Alc + ((p*256+tid)<<4));
    #pragma unroll
    for (int p=0;p<4;p++) GLDS16(bsrc[p] + ke, Blc + ((p*256+tid)<<4));
  };
  auto compute = [&](){
    #pragma unroll
    for (int kh=0;kh<2;kh++){
      bf16x8 af[8], b1[2], b3[2];
      #pragma unroll
      for (int mi=0;mi<8;mi++)
        af[mi] = *(const bf16x8*)(Alc + swz8(wm + mi*16 + (l&15), kh*4 + (l>>4)));
      #pragma unroll
      for (int ni=0;ni<2;ni++){
        b1[ni] = *(const bf16x8*)(Blc + swz8(     wn + ni*16 + (l&15), kh*4 + (l>>4)));
        b3[ni] = *(const bf16x8*)(Blc + swz8(64 + wn + ni*16 + (l&15), kh*4 + (l>>4)));
      }
      #pragma unroll
      for (int mi=0;mi<8;mi++){
        #pragma unroll
        for (int ni=0;ni<2;ni++){
          acc1[mi][ni] = __builtin_amdgcn_mfma_f32_16x16x32_bf16(af[mi], b1[ni], acc1[mi][ni], 0,0,0);
          acc3[mi][ni] = __builtin_amdgcn_mfma_f32_16x16x32_bf16(af[mi], b3[ni], acc3[mi][ni], 0,0,0);
        }
      }
    }
  };

  constexpr int NT = HD/64;                 // 16
  for (int t=0; t<NT; ++t){
    issue(t*64);
    __syncthreads();
    compute();
    __syncthreads();
  }

  #pragma unroll
  for (int mi=0;mi<8;mi++){
    #pragma unroll
    for (int ni=0;ni<2;ni++){
      #pragma unroll
      for (int r2=0;r2<4;r2++){
        const int row = wm + mi*16 + ((l>>4)<<2) + r2;
        const float rr = rvec[m0+row];
        const float v1 = rr*acc1[mi][ni][r2], v3 = rr*acc3[mi][ni][r2];
        const float h = v3 * v1 / (1.0f + expf(-v1));
        O[(size_t)(m0+row)*NF3 + n0 + wn + ni*16 + (l&15)] = f2b(h);
      }
    }
  }
}

// ---- shared down partial: Sbuf[e][t][h] = (H_e @ sw2t_e), 128x128, 1-D XCD grid ----
__global__ __launch_bounds__(256, 2) void sdown_kernel(
    const u16* __restrict__ Hb, const u16* __restrict__ W2t, float* __restrict__ Sbuf)
{
  const int b = blockIdx.x;                 // 0..511
  const int e = b & 7;
  const int r = b >> 3;                     // 0..63
  const int xt = r >> 3;                    // 0..7   (n-tile)
  const int yt = r & 7;                     // 0..7   (m-tile, innermost)
  const int m0 = yt * 128;
  const int n0 = xt * 128;
  const u16* A  = Hb  + (size_t)e*TK*NF3;
  const u16* W2 = W2t + (size_t)e*HD*NF3;

  __shared__ alignas(16) u16 Al[128*64];
  __shared__ alignas(16) u16 Bl[128*64];
  char* Alc = (char*)Al; char* Blc = (char*)Bl;

  const int tid = threadIdx.x, w = tid>>6, l = tid&63;
  const int wm = (w>>1)*64, wn = (w&1)*64;

  const u16 *asrc[4], *bsrc[4];
  #pragma unroll
  for (int p=0;p<4;p++){
    const int id = p*256 + tid;
    const int row = id>>3;
    const int chunk = (id&7)^(row&7);
    asrc[p] = A  + (size_t)(m0+row)*NF3 + chunk*8;
    bsrc[p] = W2 + (size_t)(n0+row)*NF3 + chunk*8;
  }

  f32x4 acc[4][4] = {};

  auto issue = [&](int ke){
    #pragma unroll
    for (int p=0;p<4;p++) GLDS16(asrc[p] + ke, Alc + ((p*256+tid)<<4));
    #pragma unroll
    for (int p=0;p<4;p++) GLDS16(bsrc[p] + ke, Blc + ((p*256+tid)<<4));
  };
  auto compute = [&](){
    #pragma unroll
    for (int kh=0;kh<2;kh++){
      bf16x8 af[4], bfr[4];
      #pragma unroll
      for (int mi=0;mi<4;mi++)
        af[mi]  = *(const bf16x8*)(Alc + swz8(wm + mi*16 + (l&15), kh*4 + (l>>4)));
      #pragma unroll
      for (int ni=0;ni<4;ni++)
        bfr[ni] = *(const bf16x8*)(Blc + swz8(wn + ni*16 + (l&15), kh*4 + (l>>4)));
      #pragma unroll
      for (int mi=0;mi<4;mi++){
        #pragma unroll
        for (int ni=0;ni<4;ni++)
          acc[mi][ni] = __builtin_amdgcn_mfma_f32_16x16x32_bf16(af[mi], bfr[ni], acc[mi][ni], 0,0,0);
      }
    }
  };

  constexpr int NT = NF3/64;                // 48
  for (int t=0; t<NT; ++t){
    issue(t*64);
    __syncthreads();
    compute();
    __syncthreads();
  }

  #pragma unroll
  for (int mi=0;mi<4;mi++){
    #pragma unroll
    for (int ni=0;ni<4;ni++){
      #pragma unroll
      for (int r2=0;r2<4;r2++){
        const int row = wm + mi*16 + ((l>>4)<<2) + r2;
        const int col = n0 + wn + ni*16 + (l&15);
        Sbuf[((size_t)e*TK + m0+row)*HD + col] = acc[mi][ni][r2];
      }
    }
  }
}

// ---- routed up, FUSED fp32-B transpose-convert via LDS scratch (BM=256).
// B-LDS uses bswz (conflict-fixed transpose writes).
__global__ __launch_bounds__(256, 2) void up3_kernel(
    const u16* __restrict__ xb, const float* __restrict__ W1b, const float* __restrict__ W3b,
    u16* __restrict__ Ob, const int* __restrict__ counts, const int* __restrict__ offsets,
    const int* __restrict__ tok_of)
{
  const int z  = blockIdx.z;
  const int m0 = blockIdx.y * 256;
  const int n0 = blockIdx.x * 64;
  const int Meff = counts[z];
  if (m0 >= Meff) return;
  const int off = offsets[z];
  const int* toks = tok_of + off;
  const float* W1 = W1b + (size_t)z*HD*NF2;
  const float* W3 = W3b + (size_t)z*HD*NF2;
  u16* O = Ob + (size_t)off*NF2;

  __shared__ alignas(16) u16   Al[256*64];
  __shared__ alignas(16) float Scr[2*64*64];
  __shared__ alignas(16) u16   Bl[2*64*64];
  char* Alc = (char*)Al; char* Blc = (char*)Bl; char* Scc = (char*)Scr;

  const int tid = threadIdx.x, w = tid>>6, l = tid&63;
  const int wm = (w>>1)*128, wn = (w&1)*32;

  int aofs[8];
  #pragma unroll
  for (int p=0;p<8;p++){
    const int id = p*256 + tid;
    const int row = id>>3;
    const int chunk = (id&7) ^ (row&7);
    int mg = m0 + row;
    mg = toks[(mg < Meff) ? mg : (Meff-1)];
    aofs[p] = mg*HD + chunk*8;
  }
  int bofs[8];
  #pragma unroll
  for (int p=0;p<8;p++){
    const int id = (p&3)*256 + tid;
    const int k = id>>4, c = id&15;
    bofs[p] = k*NF2 + n0 + chunkperm(c, k)*4;
  }

  f32x4 acc1[8][2] = {}; f32x4 acc3[8][2] = {};

  constexpr int NT = HD/64;
  for (int t=0; t<NT; ++t){
    #pragma unroll
    for (int p=0;p<8;p++) GLDS16(xb + aofs[p] + t*64, Alc + ((p*256+tid)<<4));
    #pragma unroll
    for (int p=0;p<4;p++) GLDS16(W1 + bofs[p] + (size_t)t*64*NF2, Scc + ((p*256+tid)<<4));
    #pragma unroll
    for (int p=4;p<8;p++) GLDS16(W3 + bofs[p] + (size_t)t*64*NF2, Scc + 16384 + (((p-4)*256+tid)<<4));
    __syncthreads();

    {
      const int nq = tid&15, kq = tid>>4;
      #pragma unroll
      for (int m2=0;m2<2;m2++){
        const char* sc = Scc + m2*16384;
        char* bd = Blc + m2*8192;
        float4 v[4];
        #pragma unroll
        for (int i=0;i<4;i++) v[i] = *(const float4*)(sc + scrofs(kq*4+i, nq));
        #pragma unroll
        for (int j=0;j<4;j++){
          const int n = nq*4+j;
          uint2 wv;
          wv.x = pk2(v[0][j], v[1][j]);
          wv.y = pk2(v[2][j], v[3][j]);
          *(uint2*)(bd + n*128 + (((kq>>1)^((n>>1)&7))<<4) + ((kq&1)<<3)) = wv;
        }
      }
    }
    __syncthreads();

    #pragma unroll
    for (int kh=0;kh<2;kh++){
      bf16x8 af[8], b1[2], b3[2];
      #pragma unroll
      for (int mi=0;mi<8;mi++)
        af[mi] = *(const bf16x8*)(Alc + swz8(wm + mi*16 + (l&15), kh*4 + (l>>4)));
      #pragma unroll
      for (int ni=0;ni<2;ni++){
        b1[ni] = *(const bf16x8*)(Blc +        bswz(wn + ni*16 + (l&15), kh*4 + (l>>4)));
        b3[ni] = *(const bf16x8*)(Blc + 8192 + bswz(wn + ni*16 + (l&15), kh*4 + (l>>4)));
      }
      #pragma unroll
      for (int mi=0;mi<8;mi++){
        #pragma unroll
        for (int ni=0;ni<2;ni++){
          acc1[mi][ni] = __builtin_amdgcn_mfma_f32_16x16x32_bf16(af[mi], b1[ni], acc1[mi][ni], 0,0,0);
          acc3[mi][ni] = __builtin_amdgcn_mfma_f32_16x16x32_bf16(af[mi], b3[ni], acc3[mi][ni], 0,0,0);
        }
      }
    }
    __syncthreads();
  }

  #pragma unroll
  for (int mi=0;mi<8;mi++){
    #pragma unroll
    for (int ni=0;ni<2;ni++){
      #pragma unroll
      for (int r2=0;r2<4;r2++){
        const int row = wm + mi*16 + ((l>>4)<<2) + r2;
        const int mg  = m0 + row;
        if (mg >= Meff) continue;
        const float v1 = acc1[mi][ni][r2], v3 = acc3[mi][ni][r2];
        const float h = v3 * v1 / (1.0f + expf(-v1));
        O[(size_t)mg*NF2 + n0 + wn + ni*16 + (l&15)] = f2b(h);
      }
    }
  }
}

// ---- routed down, FUSED fp32-B transpose-convert (bswz B-LDS): Ebuf[slot][h] = G @ rw2_e ----
__global__ __launch_bounds__(256, 2) void rdown_f_kernel(
    const u16* __restrict__ Gb, const float* __restrict__ W2b, float* __restrict__ Ebuf,
    const int* __restrict__ counts, const int* __restrict__ offsets)
{
  const int z  = blockIdx.z;
  const int m0 = blockIdx.y * 128;
  const int n0 = blockIdx.x * 64;
  const int Meff = counts[z];
  if (m0 >= Meff) return;
  const int off = offsets[z];
  const u16* A = Gb + (size_t)off*NF2;
  const float* W2 = W2b + (size_t)z*NF2*HD;

  __shared__ alignas(16) u16   Al[128*64];
  __shared__ alignas(16) float Scr[64*64];
  __shared__ alignas(16) u16   Bl[64*64];
  char* Alc = (char*)Al; char* Blc = (char*)Bl; char* Scc = (char*)Scr;

  const int tid = threadIdx.x, w = tid>>6, l = tid&63;
  const int wm = (w>>1)*64, wn = (w&1)*32;

  int aofs[4];
  #pragma unroll
  for (int p=0;p<4;p++){
    const int id = p*256 + tid;
    const int row = id>>3;
    const int chunk = (id&7) ^ (row&7);
    int mg = m0 + row; if (mg >= Meff) mg = Meff-1;
    aofs[p] = mg*NF2 + chunk*8;
  }
  int bofs[4];
  #pragma unroll
  for (int p=0;p<4;p++){
    const int id = p*256 + tid;
    const int k = id>>4, c = id&15;
    bofs[p] = k*HD + n0 + chunkperm(c, k)*4;
  }

  f32x4 acc[4][2] = {};

  constexpr int NT = NF2/64;
  for (int t=0; t<NT; ++t){
    #pragma unroll
    for (int p=0;p<4;p++) GLDS16(A + aofs[p] + t*64, Alc + ((p*256+tid)<<4));
    #pragma unroll
    for (int p=0;p<4;p++) GLDS16(W2 + bofs[p] + (size_t)t*64*HD, Scc + ((p*256+tid)<<4));
    __syncthreads();

    {
      const int nq = tid&15, kq = tid>>4;
      float4 v[4];
      #pragma unroll
      for (int i=0;i<4;i++) v[i] = *(const float4*)(Scc + scrofs(kq*4+i, nq));
      #pragma unroll
      for (int j=0;j<4;j++){
        const int n = nq*4+j;
        uint2 wv;
        wv.x = pk2(v[0][j], v[1][j]);
        wv.y = pk2(v[2][j], v[3][j]);
        *(uint2*)(Blc + n*128 + (((kq>>1)^((n>>1)&7))<<4) + ((kq&1)<<3)) = wv;
      }
    }
    __syncthreads();

    #pragma unroll
    for (int kh=0;kh<2;kh++){
      bf16x8 af[4], bfr[2];
      #pragma unroll
      for (int mi=0;mi<4;mi++)
        af[mi]  = *(const bf16x8*)(Alc + swz8(wm + mi*16 + (l&15), kh*4 + (l>>4)));
      #pragma unroll
      for (int ni=0;ni<2;ni++)
        bfr[ni] = *(const bf16x8*)(Blc + bswz(wn + ni*16 + (l&15), kh*4 + (l>>4)));
      #pragma unroll
      for (int mi=0;mi<4;mi++){
        #pragma unroll
        for (int ni=0;ni<2;ni++)
          acc[mi][ni] = __builtin_amdgcn_mfma_f32_16x16x32_bf16(af[mi], bfr[ni], acc[mi][ni], 0,0,0);
      }
    }
    __syncthreads();
  }

  #pragma unroll
  for (int mi=0;mi<4;mi++){
    #pragma unroll
    for (int ni=0;ni<2;ni++){
      #pragma unroll
      for (int r2=0;r2<4;r2++){
        const int row = wm + mi*16 + ((l>>4)<<2) + r2;
        const int mg  = m0 + row;
        if (mg >= Meff) continue;
        const int col = n0 + wn + ni*16 + (l&15);
        Ebuf[((size_t)off+mg)*HD + col] = acc[mi][ni][r2];
      }
    }
  }
}

// ---- combine: out = x + 0.125*sum_s Sbuf + sum_k wts*Ebuf[slot] ----
__global__ __launch_bounds__(256) void combine_kernel(
    const float* __restrict__ x, const float* __restrict__ Sbuf,
    const float* __restrict__ Ebuf, const float* __restrict__ wts,
    const int* __restrict__ slot_of, float* __restrict__ out)
{
  const int t = blockIdx.x, tid = threadIdx.x;
  float4 o = ((const float4*)(x + (size_t)t*HD))[tid];
  float4 s = make_float4(0.f,0.f,0.f,0.f);
  #pragma unroll
  for (int e=0;e<NSH;e++){
    const float4 v = ((const float4*)(Sbuf + ((size_t)e*TK + t)*HD))[tid];
    s.x+=v.x; s.y+=v.y; s.z+=v.z; s.w+=v.w;
  }
  o.x += 0.125f*s.x; o.y += 0.125f*s.y; o.z += 0.125f*s.z; o.w += 0.125f*s.w;
  #pragma unroll
  for (int k=0;k<KSEL;k++){
    const float wgt = wts[t*KSEL+k];
    const int slot  = slot_of[t*KSEL+k];
    const float4 v = ((const float4*)(Ebuf + (size_t)slot*HD))[tid];
    o.x += wgt*v.x; o.y += wgt*v.y; o.z += wgt*v.z; o.w += wgt*v.w;
  }
  ((float4*)(out + (size_t)t*HD))[tid] = o;
}

// ---- fallback kernels (reg-staged fp32 B) for small-ws path ----

template<int NDIM, bool ROUTED>
__global__ __launch_bounds__(256, 2) void up_kernel(
    const u16* __restrict__ Ab, const float* __restrict__ W1b, const float* __restrict__ W3b,
    u16* __restrict__ Ob, const int* __restrict__ counts, const int* __restrict__ offsets,
    const int* __restrict__ tok_of)
{
  const int z  = blockIdx.z;
  const int m0 = blockIdx.y * 128;
  const int n0 = blockIdx.x * 64;

  int Meff; const u16* A; const float *W1, *W3; u16* O; const int* toks = nullptr;
  if (ROUTED){
    Meff = counts[z];
    if (m0 >= Meff) return;
    const int off = offsets[z];
    toks = tok_of + off; A = Ab;
    W1 = W1b + (size_t)z*HD*NDIM; W3 = W3b + (size_t)z*HD*NDIM;
    O  = Ob  + (size_t)off*NDIM;
  } else {
    Meff = TK;
    A  = Ab  + (size_t)z*TK*HD;
    W1 = W1b + (size_t)z*HD*NDIM; W3 = W3b + (size_t)z*HD*NDIM;
    O  = Ob  + (size_t)z*TK*NDIM;
  }

  __shared__ alignas(16) u16 Al[128*64];
  __shared__ alignas(16) u16 Bl[128*64];
  char* Alc = (char*)Al; char* Blc = (char*)Bl;

  const int tid = threadIdx.x, w = tid>>6, l = tid&63;
  const int wm = (w>>1)*64, wn = (w&1)*32;

  const u16* asrc[4];
  #pragma unroll
  for (int p=0;p<4;p++){
    const int id  = p*256 + tid;
    const int row = id>>3;
    const int chunk = (id&7) ^ (row&7);
    int mg = m0 + row;
    if (ROUTED) mg = toks[(mg < Meff) ? mg : (Meff-1)];
    asrc[p] = A + (size_t)mg*HD + chunk*8;
  }
  const int br = tid&127, bhalf = tid>>7;
  const float* bsrc0 = ((br<64) ? W1 : W3) + (size_t)bhalf*32*NDIM + (n0 + (br&63));

  f32x4 acc1[4][2] = {}; f32x4 acc3[4][2] = {};

  auto issueA = [&](int ke){
    #pragma unroll
    for (int p=0;p<4;p++) GLDS16(asrc[p] + ke, Alc + ((p*256+tid)<<4));
  };
  auto loadB = [&](float* f, int t){
    const float* s_ = bsrc0 + (size_t)t*64*NDIM;
    #pragma unroll
    for (int i=0;i<32;i++) f[i] = s_[(size_t)i*NDIM];
  };
  auto writeB = [&](const float* f){
    #pragma unroll
    for (int j=0;j<4;j++){
      const uint4 v = make_uint4(pk2(f[j*8+0],f[j*8+1]), pk2(f[j*8+2],f[j*8+3]),
                                 pk2(f[j*8+4],f[j*8+5]), pk2(f[j*8+6],f[j*8+7]));
      *(uint4*)(Blc + swz8(br, bhalf*4+j)) = v;
    }
  };
  auto compute = [&](){
    #pragma unroll
    for (int kh=0;kh<2;kh++){
      bf16x8 af[4], b1[2], b3[2];
      #pragma unroll
      for (int mi=0;mi<4;mi++)
        af[mi] = *(const bf16x8*)(Alc + swz8(wm + mi*16 + (l&15), kh*4 + (l>>4)));
      #pragma unroll
      for (int ni=0;ni<2;ni++){
        b1[ni] = *(const bf16x8*)(Blc + swz8(     wn + ni*16 + (l&15), kh*4 + (l>>4)));
        b3[ni] = *(const bf16x8*)(Blc + swz8(64 + wn + ni*16 + (l&15), kh*4 + (l>>4)));
      }
      #pragma unroll
      for (int mi=0;mi<4;mi++){
        #pragma unroll
        for (int ni=0;ni<2;ni++){
          acc1[mi][ni] = __builtin_amdgcn_mfma_f32_16x16x32_bf16(af[mi], b1[ni], acc1[mi][ni], 0,0,0);
          acc3[mi][ni] = __builtin_amdgcn_mfma_f32_16x16x32_bf16(af[mi], b3[ni], acc3[mi][ni], 0,0,0);
        }
      }
    }
  };

  float fb[32];
  loadB(fb, 0);
  constexpr int NT = HD/64;
  for (int t=0; t<NT; ++t){
    writeB(fb);
    issueA(t*64);
    __syncthreads();
    if (t+1 < NT) loadB(fb, t+1);
    compute();
    __syncthreads();
  }

  #pragma unroll
  for (int mi=0;mi<4;mi++){
    #pragma unroll
    for (int ni=0;ni<2;ni++){
      #pragma unroll
      for (int r2=0;r2<4;r2++){
        const int row = wm + mi*16 + ((l>>4)<<2) + r2;
        const int mg  = m0 + row;
        if (ROUTED && mg >= Meff) continue;
        const float v1 = acc1[mi][ni][r2], v3 = acc3[mi][ni][r2];
        const float h = v3 * v1 / (1.0f + expf(-v1));
        O[(size_t)mg*NDIM + n0 + wn + ni*16 + (l&15)] = f2b(h);
      }
    }
  }
}

template<bool ROUTED>
__global__ __launch_bounds__(256, 2) void down_kernel(
    const u16* __restrict__ Ab, const float* __restrict__ W2b, float* __restrict__ out,
    const int* __restrict__ counts, const int* __restrict__ offsets,
    const int* __restrict__ tok_of, const float* __restrict__ wt_of)
{
  const int z  = blockIdx.z;
  const int m0 = blockIdx.y * 128;
  const int n0 = blockIdx.x * 128;
  constexpr int KT  = ROUTED ? NF2 : NF3;
  constexpr int KCH = ROUTED ? 512 : 1024;

  int Meff = TK, off = 0, e, kb;
  const u16* A; const float* W2;
  if (ROUTED){
    e = z>>2; kb = (z&3)*KCH;
    Meff = counts[e];
    if (m0 >= Meff) return;
    off = offsets[e];
    A  = Ab  + (size_t)off*NF2;
    W2 = W2b + (size_t)e*NF2*HD;
  } else {
    e = z/3; kb = (z - e*3)*KCH;
    A  = Ab  + (size_t)e*TK*NF3;
    W2 = W2b + (size_t)e*NF3*HD;
  }

  __shared__ alignas(16) u16 Al[128*64];
  __shared__ alignas(16) u16 Bl[128*64];
  char* Alc = (char*)Al; char* Blc = (char*)Bl;

  const int tid = threadIdx.x, w = tid>>6, l = tid&63;
  const int wm = (w>>1)*64, wn = (w&1)*64;

  const u16* asrc[4];
  #pragma unroll
  for (int p=0;p<4;p++){
    const int id  = p*256 + tid;
    const int row = id>>3;
    const int chunk = (id&7) ^ (row&7);
    int mg = m0 + row;
    if (ROUTED && mg >= Meff) mg = Meff-1;
    asrc[p] = A + (size_t)mg*KT + kb + chunk*8;
  }
  const int br = tid&127, bhalf = tid>>7;
  const float* bsrc0 = W2 + (size_t)(bhalf*32 + kb)*HD + (n0 + br);

  f32x4 acc[4][4] = {};

  auto issueA = [&](int ke){
    #pragma unroll
    for (int p=0;p<4;p++) GLDS16(asrc[p] + ke, Alc + ((p*256+tid)<<4));
  };
  auto loadB = [&](float* f, int t){
    const float* s_ = bsrc0 + (size_t)t*64*HD;
    #pragma unroll
    for (int i=0;i<32;i++) f[i] = s_[(size_t)i*HD];
  };
  auto writeB = [&](const float* f){
    #pragma unroll
    for (int j=0;j<4;j++){
      const uint4 v = make_uint4(pk2(f[j*8+0],f[j*8+1]), pk2(f[j*8+2],f[j*8+3]),
                                 pk2(f[j*8+4],f[j*8+5]), pk2(f[j*8+6],f[j*8+7]));
      *(uint4*)(Blc + swz8(br, bhalf*4+j)) = v;
    }
  };
  auto compute = [&](){
    #pragma unroll
    for (int kh=0;kh<2;kh++){
      bf16x8 af[4], bfr[4];
      #pragma unroll
      for (int mi=0;mi<4;mi++)
        af[mi]  = *(const bf16x8*)(Alc + swz8(wm + mi*16 + (l&15), kh*4 + (l>>4)));
      #pragma unroll
      for (int ni=0;ni<4;ni++)
        bfr[ni] = *(const bf16x8*)(Blc + swz8(wn + ni*16 + (l&15), kh*4 + (l>>4)));
      #pragma unroll
      for (int mi=0;mi<4;mi++){
        #pragma unroll
        for (int ni=0;ni<4;ni++)
          acc[mi][ni] = __builtin_amdgcn_mfma_f32_16x16x32_bf16(af[mi], bfr[ni], acc[mi][ni], 0,0,0);
      }
    }
  };

  float fb[32];
  loadB(fb, 0);
  constexpr int NT = KCH/64;
  for (int t=0; t<NT; ++t){
    writeB(fb);
    issueA(t*64);
    __syncthreads();
    if (t+1 < NT) loadB(fb, t+1);
    compute();
    __syncthreads();
  }

  #pragma unroll
  for (int mi=0;mi<4;mi++){
    #pragma unroll
    for (int ni=0;ni<4;ni++){
      #pragma unroll
      for (int r2=0;r2<4;r2++){
        const int row = wm + mi*16 + ((l>>4)<<2) + r2;
        const int mg  = m0 + row;
        const int col = n0 + wn + ni*16 + (l&15);
        if (ROUTED){
          if (mg >= Meff) continue;
          const int slot = off + mg;
          atomicAdd(&out[(size_t)tok_of[slot]*HD + col], wt_of[slot]*acc[mi][ni][r2]);
        } else {
          atomicAdd(&out[(size_t)mg*HD + col], 0.125f*acc[mi][ni][r2]);
        }
      }
    }
  }
}

// ---------------- launch ----------------

extern "C" void kernel_launch(void* const* d_in, const int* in_sizes, int n_in,
                              void* d_out, int out_size, void* d_ws, size_t ws_size,
                              hipStream_t stream)
{
  const float* x   = (const float*)d_in[0];
  const float* sn  = (const float*)d_in[1];
  const float* sw1 = (const float*)d_in[2];
  const float* sw2 = (const float*)d_in[3];
  const float* sw3 = (const float*)d_in[4];
  const float* rw1 = (const float*)d_in[5];
  const float* rw2 = (const float*)d_in[6];
  const float* rw3 = (const float*)d_in[7];
  const float* rd  = (const float*)d_in[8];
  const float* ru  = (const float*)d_in[9];
  float* out = (float*)d_out;

  char* ws = (char*)d_ws;
  u16* xb    = (u16*)(ws);                               // 2 MB
  u16* xnb   = (u16*)(ws + ((size_t)2<<20));             // 16 MB (fallback only)
  u16* Hbuf  = (u16*)(ws + ((size_t)18<<20));            // 48 MB
  u16* Gbuf  = (u16*)(ws + ((size_t)66<<20));            // 16 MB
  char* aux  = ws + ((size_t)82<<20);
  int*   sel    = (int*)(aux);
  float* wts    = (float*)(aux + 16384);
  int*   counts = (int*)(aux + 32768);
  int*   offs   = (int*)(aux + 33024);
  int*   curs   = (int*)(aux + 33280);
  int*   tok_of = (int*)(aux + 34816);
  float* wt_of  = (float*)(aux + 34816 + 16384);
  int*   slot_of= (int*)(aux + 34816 + 32768);
  float* rvec   = (float*)(aux + 34816 + 49152);
  const size_t WSLICE   = (size_t)NSH*NF3*HD*2;          // 50,331,648
  const size_t WBASE    = (size_t)84<<20;
  const size_t SBUF_OFF = WBASE + 3*WSLICE;              // 239,075,328
  const size_t SBUF_SZ  = (size_t)NSH*TK*HD*4;           // 33,554,432
  const size_t EBUF_OFF = SBUF_OFF + SBUF_SZ;
  const size_t EBUF_SZ  = (size_t)TK*KSEL*HD*4;          // 16,777,216
  const bool  full = ws_size >= EBUF_OFF + EBUF_SZ;      // ~290 MB
  u16* sw1t = (u16*)(ws + WBASE);
  u16* sw3t = (u16*)(ws + WBASE + WSLICE);
  u16* sw2t = (u16*)(ws + WBASE + 2*WSLICE);
  float* Sbuf = (float*)(ws + SBUF_OFF);
  float* Ebuf = (float*)(ws + EBUF_OFF);

  hipLaunchKernelGGL(init_kernel, dim3(1), dim3(64), 0, stream, counts, curs);
  hipLaunchKernelGGL(rms_kernel, dim3(TK), dim3(256), 0, stream, x, sn, xb, xnb, out, rvec,
                     full ? 0 : 1);
  hipLaunchKernelGGL(router_kernel, dim3(TK), dim3(64), 0, stream, x, rd, ru, sel, wts, counts);
  hipLaunchKernelGGL(scan_loss_kernel, dim3(1), dim3(64), 0, stream, counts, offs,
                     out + (size_t)TK*HD);
  hipLaunchKernelGGL(scatter_kernel, dim3(16), dim3(256), 0, stream, sel, wts, offs, curs,
                     tok_of, wt_of, slot_of);

  if (full){
    // shared weights -> bf16 [n][k]; sn folded into sw1/sw3 (round-11 known-good path)
    hipLaunchKernelGGL((convT_kernel<true>),  dim3(NF3/64, HD/64, NSH), dim3(256), 0, stream,
                       sw1, sw1t, HD, NF3, sn);
    hipLaunchKernelGGL((convT_kernel<true>),  dim3(NF3/64, HD/64, NSH), dim3(256), 0, stream,
                       sw3, sw3t, HD, NF3, sn);
    hipLaunchKernelGGL((convT_kernel<false>), dim3(HD/64, NF3/64, NSH), dim3(256), 0, stream,
                       sw2, sw2t, NF3, HD, nullptr);
    // shared up (BM=256, 1-D XCD-localized grid)
    hipLaunchKernelGGL(up2_kernel, dim3((NF3/64)*(TK/256)*NSH), dim3(256), 0, stream,
                       xb, sw1t, sw3t, Hbuf, rvec);
    // routed up: fused fp32-B transpose-convert (conflict-fixed B swizzle)
    hipLaunchKernelGGL(up3_kernel, dim3(NF2/64, 4, NEX), dim3(256), 0, stream,
                       xb, rw1, rw3, Gbuf, counts, offs, tok_of);
    // shared down partial (128x128, 1-D XCD-localized grid)
    hipLaunchKernelGGL(sdown_kernel, dim3((HD/128)*(TK/128)*NSH), dim3(256), 0, stream,
                       Hbuf, sw2t, Sbuf);
    // routed down: fused fp32-B transpose-convert (conflict-fixed), no atomics
    hipLaunchKernelGGL(rdown_f_kernel, dim3(HD/64, 8, NEX), dim3(256), 0, stream,
                       Gbuf, rw2, Ebuf, counts, offs);
    // final combine
    hipLaunchKernelGGL(combine_kernel, dim3(TK), dim3(256), 0, stream,
                       x, Sbuf, Ebuf, wts, slot_of, out);
  } else {
    hipLaunchKernelGGL((up_kernel<NF3, false>), dim3(NF3/64, TK/128, NSH), dim3(256), 0,
                       stream, xnb, sw1, sw3, Hbuf, nullptr, nullptr, nullptr);
    hipLaunchKernelGGL((up_kernel<NF2, true>), dim3(NF2/64, TK/128, NEX), dim3(256), 0,
                       stream, xb, rw1, rw3, Gbuf, counts, offs, tok_of);
    hipLaunchKernelGGL((down_kernel<false>), dim3(HD/128, TK/128, NSH*3), dim3(256), 0, stream,
                       Hbuf, sw2, out, nullptr, nullptr, nullptr, nullptr);
    hipLaunchKernelGGL((down_kernel<true>), dim3(HD/128, TK/128, NEX*4), dim3(256), 0, stream,
                       Gbuf, rw2, out, counts, offs, tok_of, wt_of);
  }
}

// Round 14
// 571.279 us; speedup vs baseline: 1.0945x; 1.0465x over previous
//
#include <hip/hip_runtime.h>
#include <hip/hip_bf16.h>
#include <math.h>

#define TK 1024
#define HD 1024
#define NF3 3072
#define NF2 2048
#define NSH 8
#define NEX 32
#define KSEL 4
#define RRK 64

typedef short bf16x8 __attribute__((ext_vector_type(8)));
typedef float f32x4 __attribute__((ext_vector_type(4)));
typedef unsigned short u16;

__device__ __forceinline__ u16 f2b(float f){
  union{float f; unsigned u;} c; c.f=f;
  unsigned r = c.u + 0x7FFFu + ((c.u>>16)&1u);
  return (u16)(r>>16);
}

__device__ __forceinline__ unsigned pk2(float a, float b){
  __hip_bfloat162 h = __float22bfloat162_rn(float2{a, b});
  union{__hip_bfloat162 h; unsigned u;} c; c.h = h; return c.u;
}

__device__ __forceinline__ int swz8(int row, int c){
  return row*128 + ((c ^ (row&7))<<4);
}
__device__ __forceinline__ int bswz(int row, int c){
  return row*128 + ((c ^ ((row>>1)&7))<<4);
}
__device__ __forceinline__ int scrofs(int k, int nq){
  return k*256 + (((nq&8) | ((nq&7)^(k&7)))<<4);
}
__device__ __forceinline__ int chunkperm(int c, int k){
  return (c&8) | ((c&7)^(k&7));
}

#define GLDS16(gptr, lptr) \
  __builtin_amdgcn_global_load_lds((const __attribute__((address_space(1))) unsigned*)(gptr), \
                                   (__attribute__((address_space(3))) unsigned*)(lptr), 16, 0, 0)

// ---------------- small kernels ----------------

__global__ void init_kernel(int* counts, int* cursors){
  int i = threadIdx.x;
  if (i < NEX){ counts[i]=0; cursors[i]=0; }
}

// FUSED rms + router: xb=bf16(x), rvec[t]=r, router top-4 -> sel/wts/counts
__global__ __launch_bounds__(256) void rmsrouter_kernel(
    const float* __restrict__ x, const float* __restrict__ rd, const float* __restrict__ ru,
    u16* __restrict__ xb, float* __restrict__ rvec,
    int* __restrict__ sel, float* __restrict__ wts, int* __restrict__ counts)
{
  const int t = blockIdx.x, tid = threadIdx.x;
  __shared__ float xl[HD];
  __shared__ float red[4];
  __shared__ float xr4[RRK][4];
  __shared__ float lg[NEX];

  const float4 v = ((const float4*)(x + (size_t)t*HD))[tid];
  xl[tid*4+0]=v.x; xl[tid*4+1]=v.y; xl[tid*4+2]=v.z; xl[tid*4+3]=v.w;
  float ss = v.x*v.x + v.y*v.y + v.z*v.z + v.w*v.w;
  #pragma unroll
  for (int m=32;m>=1;m>>=1) ss += __shfl_xor(ss, m);
  if ((tid&63)==0) red[tid>>6]=ss;
  __syncthreads();
  const float r = rsqrtf((red[0]+red[1]+red[2]+red[3])*(1.0f/HD) + 1e-6f);
  if (tid==0) rvec[t] = r;
  ushort4 o; o.x=f2b(v.x); o.y=f2b(v.y); o.z=f2b(v.z); o.w=f2b(v.w);
  ((ushort4*)(xb + (size_t)t*HD))[tid] = o;

  const int rr = tid & 63, q = tid >> 6;
  float acc = 0.f;
  const int h0 = q*256;
  for (int h=h0; h<h0+256; ++h) acc += xl[h]*rd[h*RRK + rr];
  xr4[rr][q] = acc;
  __syncthreads();
  if (tid < RRK) xr4[tid][0] = xr4[tid][0]+xr4[tid][1]+xr4[tid][2]+xr4[tid][3];
  __syncthreads();
  if (tid < NEX){
    float a=0.f;
    for (int rk=0; rk<RRK; ++rk) a += xr4[rk][0]*ru[rk*NEX + tid];
    lg[tid]=a;
  }
  __syncthreads();
  if (tid==0){
    int   sk[KSEL]; float val[KSEL]; unsigned used=0;
    for (int k=0;k<KSEL;k++){
      float best=-1e30f; int bi=0;
      for (int e=0;e<NEX;e++){
        if (used & (1u<<e)) continue;
        if (lg[e] > best){ best=lg[e]; bi=e; }
      }
      used |= (1u<<bi); sk[k]=bi; val[k]=best;
    }
    const float m = val[0];
    float w[KSEL], s=0.f;
    for (int k=0;k<KSEL;k++){ w[k]=expf(val[k]-m); s+=w[k]; }
    for (int k=0;k<KSEL;k++){
      sel[t*KSEL+k]=sk[k]; wts[t*KSEL+k]=w[k]/s;
      atomicAdd(&counts[sk[k]], 1);
    }
  }
}

// scan -> offsets + loss (1 block; cheap)
__global__ void scan_loss_kernel(const int* __restrict__ counts, int* __restrict__ offsets,
                                 float* __restrict__ out_loss)
{
  if (threadIdx.x==0){
    int off=0; float var=0.f;
    for (int e=0;e<NEX;e++){
      offsets[e]=off; off+=counts[e];
      float d = (float)counts[e] - 128.0f;
      var += d*d;
    }
    out_loss[0] = var * (1.0f/31.0f);
  }
}

__global__ void scatter_kernel(const int* __restrict__ sel, const float* __restrict__ wts,
                               const int* __restrict__ offsets, int* __restrict__ cursors,
                               int* __restrict__ tok_of, float* __restrict__ wt_of,
                               int* __restrict__ slot_of)
{
  const int id = blockIdx.x*256 + threadIdx.x;
  const int e = sel[id];
  const int pos = atomicAdd(&cursors[e], 1);
  const int slot = offsets[e] + pos;
  tok_of[slot] = id >> 2;
  wt_of[slot]  = wts[id];
  slot_of[id]  = slot;
}

// MERGED transpose-convert for sw1(+sn), sw3(+sn), sw2. Flat 1-D grid 3*8*768.
__global__ __launch_bounds__(256) void convT_all_kernel(
    const float* __restrict__ sw1, const float* __restrict__ sw3, const float* __restrict__ sw2,
    const float* __restrict__ snb,
    u16* __restrict__ sw1t, u16* __restrict__ sw3t, u16* __restrict__ sw2t)
{
  const int bid = blockIdx.x;
  const int mat = bid / (NSH*768);
  const int rem = bid - mat*(NSH*768);
  const int z = rem / 768, tt = rem - z*768;
  int K, N, n0, k0; const float* src; u16* dst; const float* snp = nullptr;
  if (mat < 2){
    K = HD; N = NF3;
    n0 = (tt % 48)*64; k0 = (tt / 48)*64;
    src = (mat ? sw3 : sw1) + (size_t)z*K*N;
    dst = (mat ? sw3t : sw1t) + (size_t)z*N*K;
    snp = snb + (size_t)z*HD + k0;
  } else {
    K = NF3; N = HD;
    n0 = (tt % 16)*64; k0 = (tt / 16)*64;
    src = sw2 + (size_t)z*K*N;
    dst = sw2t + (size_t)z*N*K;
  }
  __shared__ float tile[64][65];
  const int t = threadIdx.x;
  const int kr = t>>4, nc = t&15;
  #pragma unroll
  for (int i=0;i<4;i++){
    const int k = kr + 16*i;
    const float4 v = *(const float4*)(src + (size_t)(k0+k)*N + n0 + nc*4);
    tile[k][nc*4+0]=v.x; tile[k][nc*4+1]=v.y; tile[k][nc*4+2]=v.z; tile[k][nc*4+3]=v.w;
  }
  __syncthreads();
  const int nr = t>>3, kc = t&7;
  float sv[8];
  #pragma unroll
  for (int j=0;j<8;j++) sv[j] = snp ? snp[kc*8+j] : 1.0f;
  #pragma unroll
  for (int p=0;p<2;p++){
    const int n = nr + 32*p;
    unsigned d0 = pk2(tile[kc*8+0][n]*sv[0], tile[kc*8+1][n]*sv[1]);
    unsigned d1 = pk2(tile[kc*8+2][n]*sv[2], tile[kc*8+3][n]*sv[3]);
    unsigned d2 = pk2(tile[kc*8+4][n]*sv[4], tile[kc*8+5][n]*sv[5]);
    unsigned d3 = pk2(tile[kc*8+6][n]*sv[6], tile[kc*8+7][n]*sv[7]);
    *(uint4*)(dst + (size_t)(n0+n)*K + k0 + kc*8) = make_uint4(d0,d1,d2,d3);
  }
}

// ---- shared up: BM=256, dual-B 64 (W1|W3), dual gload_lds, 2-barrier loop ----
__global__ __launch_bounds__(256, 2) void up2_kernel(
    const u16* __restrict__ xb, const u16* __restrict__ W1t, const u16* __restrict__ W3t,
    u16* __restrict__ Ob, const float* __restrict__ rvec)
{
  const int b = blockIdx.x;
  const int z = b & 7;
  const int r = b >> 3;
  const int xt = r >> 2;
  const int yt = r & 3;
  const int m0 = yt * 256;
  const int n0 = xt * 64;
  const u16* W1 = W1t + (size_t)z*NF3*HD;
  const u16* W3 = W3t + (size_t)z*NF3*HD;
  u16* O = Ob + (size_t)z*TK*NF3;

  __shared__ alignas(16) u16 Al[256*64];
  __shared__ alignas(16) u16 Bl[128*64];
  char* Alc = (char*)Al; char* Blc = (char*)Bl;

  const int tid = threadIdx.x, w = tid>>6, l = tid&63;
  const int wm = (w>>1)*128, wn = (w&1)*32;

  const u16 *asrc[8], *bsrc[4];
  #pragma unroll
  for (int p=0;p<8;p++){
    const int id = p*256 + tid;
    const int row = id>>3;
    const int chunk = (id&7) ^ (row&7);
    asrc[p] = xb + (size_t)(m0+row)*HD + chunk*8;
  }
  #pragma unroll
  for (int p=0;p<4;p++){
    const int id = p*256 + tid;
    const int row = id>>3;
    const int chunk = (id&7) ^ (row&7);
    bsrc[p] = ((row<64) ? (W1 + (size_t)(n0+row)*HD) : (W3 + (size_t)(n0+row-64)*HD)) + chunk*8;
  }

  f32x4 acc1[8][2] = {}; f32x4 acc3[8][2] = {};

  auto issue = [&](int ke){
    #pragma unroll
    for (int p=0;p<8;p++) GLDS16(asrc[p] + ke, Alc + ((p*256+tid)<<4));
    #pragma unroll
    for (int p=0;p<4;p++) GLDS16(bsrc[p] + ke, Blc + ((p*256+tid)<<4));
  };
  auto compute = [&](){
    #pragma unroll
    for (int kh=0;kh<2;kh++){
      bf16x8 af[8], b1[2], b3[2];
      #pragma unroll
      for (int mi=0;mi<8;mi++)
        af[mi] = *(const bf16x8*)(Alc + swz8(wm + mi*16 + (l&15), kh*4 + (l>>4)));
      #pragma unroll
      for (int ni=0;ni<2;ni++){
        b1[ni] = *(const bf16x8*)(Blc + swz8(     wn + ni*16 + (l&15), kh*4 + (l>>4)));
        b3[ni] = *(const bf16x8*)(Blc + swz8(64 + wn + ni*16 + (l&15), kh*4 + (l>>4)));
      }
      #pragma unroll
      for (int mi=0;mi<8;mi++){
        #pragma unroll
        for (int ni=0;ni<2;ni++){
          acc1[mi][ni] = __builtin_amdgcn_mfma_f32_16x16x32_bf16(af[mi], b1[ni], acc1[mi][ni], 0,0,0);
          acc3[mi][ni] = __builtin_amdgcn_mfma_f32_16x16x32_bf16(af[mi], b3[ni], acc3[mi][ni], 0,0,0);
        }
      }
    }
  };

  constexpr int NT = HD/64;
  for (int t=0; t<NT; ++t){
    issue(t*64);
    __syncthreads();
    compute();
    __syncthreads();
  }

  #pragma unroll
  for (int mi=0;mi<8;mi++){
    #pragma unroll
    for (int ni=0;ni<2;ni++){
      #pragma unroll
      for (int r2=0;r2<4;r2++){
        const int row = wm + mi*16 + ((l>>4)<<2) + r2;
        const float rr = rvec[m0+row];
        const float v1 = rr*acc1[mi][ni][r2], v3 = rr*acc3[mi][ni][r2];
        const float h = v3 * v1 / (1.0f + expf(-v1));
        O[(size_t)(m0+row)*NF3 + n0 + wn + ni*16 + (l&15)] = f2b(h);
      }
    }
  }
}

// ---- shared down partial ----
__global__ __launch_bounds__(256, 2) void sdown_kernel(
    const u16* __restrict__ Hb, const u16* __restrict__ W2t, float* __restrict__ Sbuf)
{
  const int b = blockIdx.x;
  const int e = b & 7;
  const int r = b >> 3;
  const int xt = r >> 3;
  const int yt = r & 7;
  const int m0 = yt * 128;
  const int n0 = xt * 128;
  const u16* A  = Hb  + (size_t)e*TK*NF3;
  const u16* W2 = W2t + (size_t)e*HD*NF3;

  __shared__ alignas(16) u16 Al[128*64];
  __shared__ alignas(16) u16 Bl[128*64];
  char* Alc = (char*)Al; char* Blc = (char*)Bl;

  const int tid = threadIdx.x, w = tid>>6, l = tid&63;
  const int wm = (w>>1)*64, wn = (w&1)*64;

  const u16 *asrc[4], *bsrc[4];
  #pragma unroll
  for (int p=0;p<4;p++){
    const int id = p*256 + tid;
    const int row = id>>3;
    const int chunk = (id&7)^(row&7);
    asrc[p] = A  + (size_t)(m0+row)*NF3 + chunk*8;
    bsrc[p] = W2 + (size_t)(n0+row)*NF3 + chunk*8;
  }

  f32x4 acc[4][4] = {};

  auto issue = [&](int ke){
    #pragma unroll
    for (int p=0;p<4;p++) GLDS16(asrc[p] + ke, Alc + ((p*256+tid)<<4));
    #pragma unroll
    for (int p=0;p<4;p++) GLDS16(bsrc[p] + ke, Blc + ((p*256+tid)<<4));
  };
  auto compute = [&](){
    #pragma unroll
    for (int kh=0;kh<2;kh++){
      bf16x8 af[4], bfr[4];
      #pragma unroll
      for (int mi=0;mi<4;mi++)
        af[mi]  = *(const bf16x8*)(Alc + swz8(wm + mi*16 + (l&15), kh*4 + (l>>4)));
      #pragma unroll
      for (int ni=0;ni<4;ni++)
        bfr[ni] = *(const bf16x8*)(Blc + swz8(wn + ni*16 + (l&15), kh*4 + (l>>4)));
      #pragma unroll
      for (int mi=0;mi<4;mi++){
        #pragma unroll
        for (int ni=0;ni<4;ni++)
          acc[mi][ni] = __builtin_amdgcn_mfma_f32_16x16x32_bf16(af[mi], bfr[ni], acc[mi][ni], 0,0,0);
      }
    }
  };

  constexpr int NT = NF3/64;
  for (int t=0; t<NT; ++t){
    issue(t*64);
    __syncthreads();
    compute();
    __syncthreads();
  }

  #pragma unroll
  for (int mi=0;mi<4;mi++){
    #pragma unroll
    for (int ni=0;ni<4;ni++){
      #pragma unroll
      for (int r2=0;r2<4;r2++){
        const int row = wm + mi*16 + ((l>>4)<<2) + r2;
        const int col = n0 + wn + ni*16 + (l&15);
        Sbuf[((size_t)e*TK + m0+row)*HD + col] = acc[mi][ni][r2];
      }
    }
  }
}

// ---- routed up, fused fp32-B transpose-convert (bswz) ----
__global__ __launch_bounds__(256, 2) void up3_kernel(
    const u16* __restrict__ xb, const float* __restrict__ W1b, const float* __restrict__ W3b,
    u16* __restrict__ Ob, const int* __restrict__ counts, const int* __restrict__ offsets,
    const int* __restrict__ tok_of)
{
  const int z  = blockIdx.z;
  const int m0 = blockIdx.y * 256;
  const int n0 = blockIdx.x * 64;
  const int Meff = counts[z];
  if (m0 >= Meff) return;
  const int off = offsets[z];
  const int* toks = tok_of + off;
  const float* W1 = W1b + (size_t)z*HD*NF2;
  const float* W3 = W3b + (size_t)z*HD*NF2;
  u16* O = Ob + (size_t)off*NF2;

  __shared__ alignas(16) u16   Al[256*64];
  __shared__ alignas(16) float Scr[2*64*64];
  __shared__ alignas(16) u16   Bl[2*64*64];
  char* Alc = (char*)Al; char* Blc = (char*)Bl; char* Scc = (char*)Scr;

  const int tid = threadIdx.x, w = tid>>6, l = tid&63;
  const int wm = (w>>1)*128, wn = (w&1)*32;

  int aofs[8];
  #pragma unroll
  for (int p=0;p<8;p++){
    const int id = p*256 + tid;
    const int row = id>>3;
    const int chunk = (id&7) ^ (row&7);
    int mg = m0 + row;
    mg = toks[(mg < Meff) ? mg : (Meff-1)];
    aofs[p] = mg*HD + chunk*8;
  }
  int bofs[8];
  #pragma unroll
  for (int p=0;p<8;p++){
    const int id = (p&3)*256 + tid;
    const int k = id>>4, c = id&15;
    bofs[p] = k*NF2 + n0 + chunkperm(c, k)*4;
  }

  f32x4 acc1[8][2] = {}; f32x4 acc3[8][2] = {};

  constexpr int NT = HD/64;
  for (int t=0; t<NT; ++t){
    #pragma unroll
    for (int p=0;p<8;p++) GLDS16(xb + aofs[p] + t*64, Alc + ((p*256+tid)<<4));
    #pragma unroll
    for (int p=0;p<4;p++) GLDS16(W1 + bofs[p] + (size_t)t*64*NF2, Scc + ((p*256+tid)<<4));
    #pragma unroll
    for (int p=4;p<8;p++) GLDS16(W3 + bofs[p] + (size_t)t*64*NF2, Scc + 16384 + (((p-4)*256+tid)<<4));
    __syncthreads();

    {
      const int nq = tid&15, kq = tid>>4;
      #pragma unroll
      for (int m2=0;m2<2;m2++){
        const char* sc = Scc + m2*16384;
        char* bd = Blc + m2*8192;
        float4 v[4];
        #pragma unroll
        for (int i=0;i<4;i++) v[i] = *(const float4*)(sc + scrofs(kq*4+i, nq));
        #pragma unroll
        for (int j=0;j<4;j++){
          const int n = nq*4+j;
          uint2 wv;
          wv.x = pk2(v[0][j], v[1][j]);
          wv.y = pk2(v[2][j], v[3][j]);
          *(uint2*)(bd + n*128 + (((kq>>1)^((n>>1)&7))<<4) + ((kq&1)<<3)) = wv;
        }
      }
    }
    __syncthreads();

    #pragma unroll
    for (int kh=0;kh<2;kh++){
      bf16x8 af[8], b1[2], b3[2];
      #pragma unroll
      for (int mi=0;mi<8;mi++)
        af[mi] = *(const bf16x8*)(Alc + swz8(wm + mi*16 + (l&15), kh*4 + (l>>4)));
      #pragma unroll
      for (int ni=0;ni<2;ni++){
        b1[ni] = *(const bf16x8*)(Blc +        bswz(wn + ni*16 + (l&15), kh*4 + (l>>4)));
        b3[ni] = *(const bf16x8*)(Blc + 8192 + bswz(wn + ni*16 + (l&15), kh*4 + (l>>4)));
      }
      #pragma unroll
      for (int mi=0;mi<8;mi++){
        #pragma unroll
        for (int ni=0;ni<2;ni++){
          acc1[mi][ni] = __builtin_amdgcn_mfma_f32_16x16x32_bf16(af[mi], b1[ni], acc1[mi][ni], 0,0,0);
          acc3[mi][ni] = __builtin_amdgcn_mfma_f32_16x16x32_bf16(af[mi], b3[ni], acc3[mi][ni], 0,0,0);
        }
      }
    }
    __syncthreads();
  }

  #pragma unroll
  for (int mi=0;mi<8;mi++){
    #pragma unroll
    for (int ni=0;ni<2;ni++){
      #pragma unroll
      for (int r2=0;r2<4;r2++){
        const int row = wm + mi*16 + ((l>>4)<<2) + r2;
        const int mg  = m0 + row;
        if (mg >= Meff) continue;
        const float v1 = acc1[mi][ni][r2], v3 = acc3[mi][ni][r2];
        const float h = v3 * v1 / (1.0f + expf(-v1));
        O[(size_t)mg*NF2 + n0 + wn + ni*16 + (l&15)] = f2b(h);
      }
    }
  }
}

// ---- routed down, fused fp32-B transpose-convert (bswz) ----
__global__ __launch_bounds__(256, 2) void rdown_f_kernel(
    const u16* __restrict__ Gb, const float* __restrict__ W2b, float* __restrict__ Ebuf,
    const int* __restrict__ counts, const int* __restrict__ offsets)
{
  const int z  = blockIdx.z;
  const int m0 = blockIdx.y * 128;
  const int n0 = blockIdx.x * 64;
  const int Meff = counts[z];
  if (m0 >= Meff) return;
  const int off = offsets[z];
  const u16* A = Gb + (size_t)off*NF2;
  const float* W2 = W2b + (size_t)z*NF2*HD;

  __shared__ alignas(16) u16   Al[128*64];
  __shared__ alignas(16) float Scr[64*64];
  __shared__ alignas(16) u16   Bl[64*64];
  char* Alc = (char*)Al; char* Blc = (char*)Bl; char* Scc = (char*)Scr;

  const int tid = threadIdx.x, w = tid>>6, l = tid&63;
  const int wm = (w>>1)*64, wn = (w&1)*32;

  int aofs[4];
  #pragma unroll
  for (int p=0;p<4;p++){
    const int id = p*256 + tid;
    const int row = id>>3;
    const int chunk = (id&7) ^ (row&7);
    int mg = m0 + row; if (mg >= Meff) mg = Meff-1;
    aofs[p] = mg*NF2 + chunk*8;
  }
  int bofs[4];
  #pragma unroll
  for (int p=0;p<4;p++){
    const int id = p*256 + tid;
    const int k = id>>4, c = id&15;
    bofs[p] = k*HD + n0 + chunkperm(c, k)*4;
  }

  f32x4 acc[4][2] = {};

  constexpr int NT = NF2/64;
  for (int t=0; t<NT; ++t){
    #pragma unroll
    for (int p=0;p<4;p++) GLDS16(A + aofs[p] + t*64, Alc + ((p*256+tid)<<4));
    #pragma unroll
    for (int p=0;p<4;p++) GLDS16(W2 + bofs[p] + (size_t)t*64*HD, Scc + ((p*256+tid)<<4));
    __syncthreads();

    {
      const int nq = tid&15, kq = tid>>4;
      float4 v[4];
      #pragma unroll
      for (int i=0;i<4;i++) v[i] = *(const float4*)(Scc + scrofs(kq*4+i, nq));
      #pragma unroll
      for (int j=0;j<4;j++){
        const int n = nq*4+j;
        uint2 wv;
        wv.x = pk2(v[0][j], v[1][j]);
        wv.y = pk2(v[2][j], v[3][j]);
        *(uint2*)(Blc + n*128 + (((kq>>1)^((n>>1)&7))<<4) + ((kq&1)<<3)) = wv;
      }
    }
    __syncthreads();

    #pragma unroll
    for (int kh=0;kh<2;kh++){
      bf16x8 af[4], bfr[2];
      #pragma unroll
      for (int mi=0;mi<4;mi++)
        af[mi]  = *(const bf16x8*)(Alc + swz8(wm + mi*16 + (l&15), kh*4 + (l>>4)));
      #pragma unroll
      for (int ni=0;ni<2;ni++)
        bfr[ni] = *(const bf16x8*)(Blc + bswz(wn + ni*16 + (l&15), kh*4 + (l>>4)));
      #pragma unroll
      for (int mi=0;mi<4;mi++){
        #pragma unroll
        for (int ni=0;ni<2;ni++)
          acc[mi][ni] = __builtin_amdgcn_mfma_f32_16x16x32_bf16(af[mi], bfr[ni], acc[mi][ni], 0,0,0);
      }
    }
    __syncthreads();
  }

  #pragma unroll
  for (int mi=0;mi<4;mi++){
    #pragma unroll
    for (int ni=0;ni<2;ni++){
      #pragma unroll
      for (int r2=0;r2<4;r2++){
        const int row = wm + mi*16 + ((l>>4)<<2) + r2;
        const int mg  = m0 + row;
        if (mg >= Meff) continue;
        const int col = n0 + wn + ni*16 + (l&15);
        Ebuf[((size_t)off+mg)*HD + col] = acc[mi][ni][r2];
      }
    }
  }
}

// ---- combine ----
__global__ __launch_bounds__(256) void combine_kernel(
    const float* __restrict__ x, const float* __restrict__ Sbuf,
    const float* __restrict__ Ebuf, const float* __restrict__ wts,
    const int* __restrict__ slot_of, float* __restrict__ out)
{
  const int t = blockIdx.x, tid = threadIdx.x;
  float4 o = ((const float4*)(x + (size_t)t*HD))[tid];
  float4 s = make_float4(0.f,0.f,0.f,0.f);
  #pragma unroll
  for (int e=0;e<NSH;e++){
    const float4 v = ((const float4*)(Sbuf + ((size_t)e*TK + t)*HD))[tid];
    s.x+=v.x; s.y+=v.y; s.z+=v.z; s.w+=v.w;
  }
  o.x += 0.125f*s.x; o.y += 0.125f*s.y; o.z += 0.125f*s.z; o.w += 0.125f*s.w;
  #pragma unroll
  for (int k=0;k<KSEL;k++){
    const float wgt = wts[t*KSEL+k];
    const int slot  = slot_of[t*KSEL+k];
    const float4 v = ((const float4*)(Ebuf + (size_t)slot*HD))[tid];
    o.x += wgt*v.x; o.y += wgt*v.y; o.z += wgt*v.z; o.w += wgt*v.w;
  }
  ((float4*)(out + (size_t)t*HD))[tid] = o;
}

// ---------------- launch ----------------

extern "C" void kernel_launch(void* const* d_in, const int* in_sizes, int n_in,
                              void* d_out, int out_size, void* d_ws, size_t ws_size,
                              hipStream_t stream)
{
  const float* x   = (const float*)d_in[0];
  const float* sn  = (const float*)d_in[1];
  const float* sw1 = (const float*)d_in[2];
  const float* sw2 = (const float*)d_in[3];
  const float* sw3 = (const float*)d_in[4];
  const float* rw1 = (const float*)d_in[5];
  const float* rw2 = (const float*)d_in[6];
  const float* rw3 = (const float*)d_in[7];
  const float* rd  = (const float*)d_in[8];
  const float* ru  = (const float*)d_in[9];
  float* out = (float*)d_out;

  char* ws = (char*)d_ws;
  u16* xb    = (u16*)(ws);                               // 2 MB
  u16* Hbuf  = (u16*)(ws + ((size_t)18<<20));            // 48 MB
  u16* Gbuf  = (u16*)(ws + ((size_t)66<<20));            // 16 MB
  char* aux  = ws + ((size_t)82<<20);
  int*   sel    = (int*)(aux);
  float* wts    = (float*)(aux + 16384);
  int*   counts = (int*)(aux + 32768);
  int*   offs   = (int*)(aux + 33024);
  int*   curs   = (int*)(aux + 33280);
  int*   tok_of = (int*)(aux + 34816);
  float* wt_of  = (float*)(aux + 34816 + 16384);
  int*   slot_of= (int*)(aux + 34816 + 32768);
  float* rvec   = (float*)(aux + 34816 + 49152);
  const size_t WSLICE   = (size_t)NSH*NF3*HD*2;          // 50,331,648
  const size_t WBASE    = (size_t)84<<20;
  const size_t SBUF_OFF = WBASE + 3*WSLICE;
  const size_t SBUF_SZ  = (size_t)NSH*TK*HD*4;
  const size_t EBUF_OFF = SBUF_OFF + SBUF_SZ;
  u16* sw1t = (u16*)(ws + WBASE);
  u16* sw3t = (u16*)(ws + WBASE + WSLICE);
  u16* sw2t = (u16*)(ws + WBASE + 2*WSLICE);
  float* Sbuf = (float*)(ws + SBUF_OFF);
  float* Ebuf = (float*)(ws + EBUF_OFF);

  hipLaunchKernelGGL(init_kernel, dim3(1), dim3(64), 0, stream, counts, curs);
  // fused rms+router
  hipLaunchKernelGGL(rmsrouter_kernel, dim3(TK), dim3(256), 0, stream,
                     x, rd, ru, xb, rvec, sel, wts, counts);
  // scan (offsets for up3/rdown_f) + loss
  hipLaunchKernelGGL(scan_loss_kernel, dim3(1), dim3(64), 0, stream, counts, offs,
                     out + (size_t)TK*HD);
  hipLaunchKernelGGL(scatter_kernel, dim3(16), dim3(256), 0, stream, sel, wts, offs, curs,
                     tok_of, wt_of, slot_of);
  // merged weight conversion (sw1+sn | sw3+sn | sw2)
  hipLaunchKernelGGL(convT_all_kernel, dim3(3*NSH*768), dim3(256), 0, stream,
                     sw1, sw3, sw2, sn, sw1t, sw3t, sw2t);
  // shared up
  hipLaunchKernelGGL(up2_kernel, dim3((NF3/64)*(TK/256)*NSH), dim3(256), 0, stream,
                     xb, sw1t, sw3t, Hbuf, rvec);
  // routed up
  hipLaunchKernelGGL(up3_kernel, dim3(NF2/64, 4, NEX), dim3(256), 0, stream,
                     xb, rw1, rw3, Gbuf, counts, offs, tok_of);
  // shared down partial
  hipLaunchKernelGGL(sdown_kernel, dim3((HD/128)*(TK/128)*NSH), dim3(256), 0, stream,
                     Hbuf, sw2t, Sbuf);
  // routed down partial
  hipLaunchKernelGGL(rdown_f_kernel, dim3(HD/64, 8, NEX), dim3(256), 0, stream,
                     Gbuf, rw2, Ebuf, counts, offs);
  // combine
  hipLaunchKernelGGL(combine_kernel, dim3(TK), dim3(256), 0, stream,
                     x, Sbuf, Ebuf, wts, slot_of, out);
}

// Round 15
// 551.718 us; speedup vs baseline: 1.1333x; 1.0355x over previous
//
#include <hip/hip_runtime.h>
#include <hip/hip_bf16.h>
#include <math.h>

#define TK 1024
#define HD 1024
#define NF3 3072
#define NF2 2048
#define NSH 8
#define NEX 32
#define KSEL 4
#define RRK 64

typedef short bf16x8 __attribute__((ext_vector_type(8)));
typedef float f32x4 __attribute__((ext_vector_type(4)));
typedef unsigned short u16;

__device__ __forceinline__ u16 f2b(float f){
  union{float f; unsigned u;} c; c.f=f;
  unsigned r = c.u + 0x7FFFu + ((c.u>>16)&1u);
  return (u16)(r>>16);
}

__device__ __forceinline__ unsigned pk2(float a, float b){
  __hip_bfloat162 h = __float22bfloat162_rn(float2{a, b});
  union{__hip_bfloat162 h; unsigned u;} c; c.h = h; return c.u;
}

__device__ __forceinline__ int swz8(int row, int c){
  return row*128 + ((c ^ (row&7))<<4);
}
__device__ __forceinline__ int bswz(int row, int c){
  return row*128 + ((c ^ ((row>>1)&7))<<4);
}
__device__ __forceinline__ int scrofs(int k, int nq){
  return k*256 + (((nq&8) | ((nq&7)^(k&7)))<<4);
}
__device__ __forceinline__ int chunkperm(int c, int k){
  return (c&8) | ((c&7)^(k&7));
}

#define GLDS16(gptr, lptr) \
  __builtin_amdgcn_global_load_lds((const __attribute__((address_space(1))) unsigned*)(gptr), \
                                   (__attribute__((address_space(3))) unsigned*)(lptr), 16, 0, 0)

// ---------------- small kernels ----------------

__global__ void init_kernel(int* counts, int* cursors){
  int i = threadIdx.x;
  if (i < NEX){ counts[i]=0; cursors[i]=0; }
}

// FUSED rms + router: xb=bf16(x), rvec[t]=r, router top-4 -> sel/wts/counts
__global__ __launch_bounds__(256) void rmsrouter_kernel(
    const float* __restrict__ x, const float* __restrict__ rd, const float* __restrict__ ru,
    u16* __restrict__ xb, float* __restrict__ rvec,
    int* __restrict__ sel, float* __restrict__ wts, int* __restrict__ counts)
{
  const int t = blockIdx.x, tid = threadIdx.x;
  __shared__ float xl[HD];
  __shared__ float red[4];
  __shared__ float xr4[RRK][4];
  __shared__ float lg[NEX];

  const float4 v = ((const float4*)(x + (size_t)t*HD))[tid];
  xl[tid*4+0]=v.x; xl[tid*4+1]=v.y; xl[tid*4+2]=v.z; xl[tid*4+3]=v.w;
  float ss = v.x*v.x + v.y*v.y + v.z*v.z + v.w*v.w;
  #pragma unroll
  for (int m=32;m>=1;m>>=1) ss += __shfl_xor(ss, m);
  if ((tid&63)==0) red[tid>>6]=ss;
  __syncthreads();
  const float r = rsqrtf((red[0]+red[1]+red[2]+red[3])*(1.0f/HD) + 1e-6f);
  if (tid==0) rvec[t] = r;
  ushort4 o; o.x=f2b(v.x); o.y=f2b(v.y); o.z=f2b(v.z); o.w=f2b(v.w);
  ((ushort4*)(xb + (size_t)t*HD))[tid] = o;

  const int rr = tid & 63, q = tid >> 6;
  float acc = 0.f;
  const int h0 = q*256;
  for (int h=h0; h<h0+256; ++h) acc += xl[h]*rd[h*RRK + rr];
  xr4[rr][q] = acc;
  __syncthreads();
  if (tid < RRK) xr4[tid][0] = xr4[tid][0]+xr4[tid][1]+xr4[tid][2]+xr4[tid][3];
  __syncthreads();
  if (tid < NEX){
    float a=0.f;
    for (int rk=0; rk<RRK; ++rk) a += xr4[rk][0]*ru[rk*NEX + tid];
    lg[tid]=a;
  }
  __syncthreads();
  if (tid==0){
    int   sk[KSEL]; float val[KSEL]; unsigned used=0;
    for (int k=0;k<KSEL;k++){
      float best=-1e30f; int bi=0;
      for (int e=0;e<NEX;e++){
        if (used & (1u<<e)) continue;
        if (lg[e] > best){ best=lg[e]; bi=e; }
      }
      used |= (1u<<bi); sk[k]=bi; val[k]=best;
    }
    const float m = val[0];
    float w[KSEL], s=0.f;
    for (int k=0;k<KSEL;k++){ w[k]=expf(val[k]-m); s+=w[k]; }
    for (int k=0;k<KSEL;k++){
      sel[t*KSEL+k]=sk[k]; wts[t*KSEL+k]=w[k]/s;
      atomicAdd(&counts[sk[k]], 1);
    }
  }
}

// scatter with LOCAL scan; block 0 also writes global offsets + loss.
__global__ void scatter2_kernel(const int* __restrict__ sel, const float* __restrict__ wts,
                                const int* __restrict__ counts, int* __restrict__ cursors,
                                int* __restrict__ offsets,
                                int* __restrict__ tok_of, float* __restrict__ wt_of,
                                int* __restrict__ slot_of, float* __restrict__ out_loss)
{
  __shared__ int offs_l[NEX];
  if (threadIdx.x==0){
    int off=0; float var=0.f;
    for (int e=0;e<NEX;e++){
      offs_l[e]=off;
      if (blockIdx.x==0) offsets[e]=off;
      off+=counts[e];
      float d = (float)counts[e] - 128.0f;
      var += d*d;
    }
    if (blockIdx.x==0) out_loss[0] = var * (1.0f/31.0f);
  }
  __syncthreads();
  const int id = blockIdx.x*256 + threadIdx.x;
  const int e = sel[id];
  const int pos = atomicAdd(&cursors[e], 1);
  const int slot = offs_l[e] + pos;
  tok_of[slot] = id >> 2;
  wt_of[slot]  = wts[id];
  slot_of[id]  = slot;
}

// MERGED transpose-convert for sw1(+sn), sw3(+sn), sw2. Flat 1-D grid 3*8*768.
__global__ __launch_bounds__(256) void convT_all_kernel(
    const float* __restrict__ sw1, const float* __restrict__ sw3, const float* __restrict__ sw2,
    const float* __restrict__ snb,
    u16* __restrict__ sw1t, u16* __restrict__ sw3t, u16* __restrict__ sw2t)
{
  const int bid = blockIdx.x;
  const int mat = bid / (NSH*768);
  const int rem = bid - mat*(NSH*768);
  const int z = rem / 768, tt = rem - z*768;
  int K, N, n0, k0; const float* src; u16* dst; const float* snp = nullptr;
  if (mat < 2){
    K = HD; N = NF3;
    n0 = (tt % 48)*64; k0 = (tt / 48)*64;
    src = (mat ? sw3 : sw1) + (size_t)z*K*N;
    dst = (mat ? sw3t : sw1t) + (size_t)z*N*K;
    snp = snb + (size_t)z*HD + k0;
  } else {
    K = NF3; N = HD;
    n0 = (tt % 16)*64; k0 = (tt / 16)*64;
    src = sw2 + (size_t)z*K*N;
    dst = sw2t + (size_t)z*N*K;
  }
  __shared__ float tile[64][65];
  const int t = threadIdx.x;
  const int kr = t>>4, nc = t&15;
  #pragma unroll
  for (int i=0;i<4;i++){
    const int k = kr + 16*i;
    const float4 v = *(const float4*)(src + (size_t)(k0+k)*N + n0 + nc*4);
    tile[k][nc*4+0]=v.x; tile[k][nc*4+1]=v.y; tile[k][nc*4+2]=v.z; tile[k][nc*4+3]=v.w;
  }
  __syncthreads();
  const int nr = t>>3, kc = t&7;
  float sv[8];
  #pragma unroll
  for (int j=0;j<8;j++) sv[j] = snp ? snp[kc*8+j] : 1.0f;
  #pragma unroll
  for (int p=0;p<2;p++){
    const int n = nr + 32*p;
    unsigned d0 = pk2(tile[kc*8+0][n]*sv[0], tile[kc*8+1][n]*sv[1]);
    unsigned d1 = pk2(tile[kc*8+2][n]*sv[2], tile[kc*8+3][n]*sv[3]);
    unsigned d2 = pk2(tile[kc*8+4][n]*sv[4], tile[kc*8+5][n]*sv[5]);
    unsigned d3 = pk2(tile[kc*8+6][n]*sv[6], tile[kc*8+7][n]*sv[7]);
    *(uint4*)(dst + (size_t)(n0+n)*K + k0 + kc*8) = make_uint4(d0,d1,d2,d3);
  }
}

// ---- shared up: BM=256, dual-B 64 (W1|W3), dual gload_lds, 2-barrier loop ----
__global__ __launch_bounds__(256, 2) void up2_kernel(
    const u16* __restrict__ xb, const u16* __restrict__ W1t, const u16* __restrict__ W3t,
    u16* __restrict__ Ob, const float* __restrict__ rvec)
{
  const int b = blockIdx.x;
  const int z = b & 7;
  const int r = b >> 3;
  const int xt = r >> 2;
  const int yt = r & 3;
  const int m0 = yt * 256;
  const int n0 = xt * 64;
  const u16* W1 = W1t + (size_t)z*NF3*HD;
  const u16* W3 = W3t + (size_t)z*NF3*HD;
  u16* O = Ob + (size_t)z*TK*NF3;

  __shared__ alignas(16) u16 Al[256*64];
  __shared__ alignas(16) u16 Bl[128*64];
  char* Alc = (char*)Al; char* Blc = (char*)Bl;

  const int tid = threadIdx.x, w = tid>>6, l = tid&63;
  const int wm = (w>>1)*128, wn = (w&1)*32;

  const u16 *asrc[8], *bsrc[4];
  #pragma unroll
  for (int p=0;p<8;p++){
    const int id = p*256 + tid;
    const int row = id>>3;
    const int chunk = (id&7) ^ (row&7);
    asrc[p] = xb + (size_t)(m0+row)*HD + chunk*8;
  }
  #pragma unroll
  for (int p=0;p<4;p++){
    const int id = p*256 + tid;
    const int row = id>>3;
    const int chunk = (id&7) ^ (row&7);
    bsrc[p] = ((row<64) ? (W1 + (size_t)(n0+row)*HD) : (W3 + (size_t)(n0+row-64)*HD)) + chunk*8;
  }

  f32x4 acc1[8][2] = {}; f32x4 acc3[8][2] = {};

  auto issue = [&](int ke){
    #pragma unroll
    for (int p=0;p<8;p++) GLDS16(asrc[p] + ke, Alc + ((p*256+tid)<<4));
    #pragma unroll
    for (int p=0;p<4;p++) GLDS16(bsrc[p] + ke, Blc + ((p*256+tid)<<4));
  };
  auto compute = [&](){
    #pragma unroll
    for (int kh=0;kh<2;kh++){
      bf16x8 af[8], b1[2], b3[2];
      #pragma unroll
      for (int mi=0;mi<8;mi++)
        af[mi] = *(const bf16x8*)(Alc + swz8(wm + mi*16 + (l&15), kh*4 + (l>>4)));
      #pragma unroll
      for (int ni=0;ni<2;ni++){
        b1[ni] = *(const bf16x8*)(Blc + swz8(     wn + ni*16 + (l&15), kh*4 + (l>>4)));
        b3[ni] = *(const bf16x8*)(Blc + swz8(64 + wn + ni*16 + (l&15), kh*4 + (l>>4)));
      }
      #pragma unroll
      for (int mi=0;mi<8;mi++){
        #pragma unroll
        for (int ni=0;ni<2;ni++){
          acc1[mi][ni] = __builtin_amdgcn_mfma_f32_16x16x32_bf16(af[mi], b1[ni], acc1[mi][ni], 0,0,0);
          acc3[mi][ni] = __builtin_amdgcn_mfma_f32_16x16x32_bf16(af[mi], b3[ni], acc3[mi][ni], 0,0,0);
        }
      }
    }
  };

  constexpr int NT = HD/64;
  for (int t=0; t<NT; ++t){
    issue(t*64);
    __syncthreads();
    compute();
    __syncthreads();
  }

  #pragma unroll
  for (int mi=0;mi<8;mi++){
    #pragma unroll
    for (int ni=0;ni<2;ni++){
      #pragma unroll
      for (int r2=0;r2<4;r2++){
        const int row = wm + mi*16 + ((l>>4)<<2) + r2;
        const float rr = rvec[m0+row];
        const float v1 = rr*acc1[mi][ni][r2], v3 = rr*acc3[mi][ni][r2];
        const float h = v3 * v1 / (1.0f + expf(-v1));
        O[(size_t)(m0+row)*NF3 + n0 + wn + ni*16 + (l&15)] = f2b(h);
      }
    }
  }
}

// ---- routed up, fused fp32-B transpose-convert (bswz) ----
__global__ __launch_bounds__(256, 2) void up3_kernel(
    const u16* __restrict__ xb, const float* __restrict__ W1b, const float* __restrict__ W3b,
    u16* __restrict__ Ob, const int* __restrict__ counts, const int* __restrict__ offsets,
    const int* __restrict__ tok_of)
{
  const int z  = blockIdx.z;
  const int m0 = blockIdx.y * 256;
  const int n0 = blockIdx.x * 64;
  const int Meff = counts[z];
  if (m0 >= Meff) return;
  const int off = offsets[z];
  const int* toks = tok_of + off;
  const float* W1 = W1b + (size_t)z*HD*NF2;
  const float* W3 = W3b + (size_t)z*HD*NF2;
  u16* O = Ob + (size_t)off*NF2;

  __shared__ alignas(16) u16   Al[256*64];
  __shared__ alignas(16) float Scr[2*64*64];
  __shared__ alignas(16) u16   Bl[2*64*64];
  char* Alc = (char*)Al; char* Blc = (char*)Bl; char* Scc = (char*)Scr;

  const int tid = threadIdx.x, w = tid>>6, l = tid&63;
  const int wm = (w>>1)*128, wn = (w&1)*32;

  int aofs[8];
  #pragma unroll
  for (int p=0;p<8;p++){
    const int id = p*256 + tid;
    const int row = id>>3;
    const int chunk = (id&7) ^ (row&7);
    int mg = m0 + row;
    mg = toks[(mg < Meff) ? mg : (Meff-1)];
    aofs[p] = mg*HD + chunk*8;
  }
  int bofs[8];
  #pragma unroll
  for (int p=0;p<8;p++){
    const int id = (p&3)*256 + tid;
    const int k = id>>4, c = id&15;
    bofs[p] = k*NF2 + n0 + chunkperm(c, k)*4;
  }

  f32x4 acc1[8][2] = {}; f32x4 acc3[8][2] = {};

  constexpr int NT = HD/64;
  for (int t=0; t<NT; ++t){
    #pragma unroll
    for (int p=0;p<8;p++) GLDS16(xb + aofs[p] + t*64, Alc + ((p*256+tid)<<4));
    #pragma unroll
    for (int p=0;p<4;p++) GLDS16(W1 + bofs[p] + (size_t)t*64*NF2, Scc + ((p*256+tid)<<4));
    #pragma unroll
    for (int p=4;p<8;p++) GLDS16(W3 + bofs[p] + (size_t)t*64*NF2, Scc + 16384 + (((p-4)*256+tid)<<4));
    __syncthreads();

    {
      const int nq = tid&15, kq = tid>>4;
      #pragma unroll
      for (int m2=0;m2<2;m2++){
        const char* sc = Scc + m2*16384;
        char* bd = Blc + m2*8192;
        float4 v[4];
        #pragma unroll
        for (int i=0;i<4;i++) v[i] = *(const float4*)(sc + scrofs(kq*4+i, nq));
        #pragma unroll
        for (int j=0;j<4;j++){
          const int n = nq*4+j;
          uint2 wv;
          wv.x = pk2(v[0][j], v[1][j]);
          wv.y = pk2(v[2][j], v[3][j]);
          *(uint2*)(bd + n*128 + (((kq>>1)^((n>>1)&7))<<4) + ((kq&1)<<3)) = wv;
        }
      }
    }
    __syncthreads();

    #pragma unroll
    for (int kh=0;kh<2;kh++){
      bf16x8 af[8], b1[2], b3[2];
      #pragma unroll
      for (int mi=0;mi<8;mi++)
        af[mi] = *(const bf16x8*)(Alc + swz8(wm + mi*16 + (l&15), kh*4 + (l>>4)));
      #pragma unroll
      for (int ni=0;ni<2;ni++){
        b1[ni] = *(const bf16x8*)(Blc +        bswz(wn + ni*16 + (l&15), kh*4 + (l>>4)));
        b3[ni] = *(const bf16x8*)(Blc + 8192 + bswz(wn + ni*16 + (l&15), kh*4 + (l>>4)));
      }
      #pragma unroll
      for (int mi=0;mi<8;mi++){
        #pragma unroll
        for (int ni=0;ni<2;ni++){
          acc1[mi][ni] = __builtin_amdgcn_mfma_f32_16x16x32_bf16(af[mi], b1[ni], acc1[mi][ni], 0,0,0);
          acc3[mi][ni] = __builtin_amdgcn_mfma_f32_16x16x32_bf16(af[mi], b3[ni], acc3[mi][ni], 0,0,0);
        }
      }
    }
    __syncthreads();
  }

  #pragma unroll
  for (int mi=0;mi<8;mi++){
    #pragma unroll
    for (int ni=0;ni<2;ni++){
      #pragma unroll
      for (int r2=0;r2<4;r2++){
        const int row = wm + mi*16 + ((l>>4)<<2) + r2;
        const int mg  = m0 + row;
        if (mg >= Meff) continue;
        const float v1 = acc1[mi][ni][r2], v3 = acc3[mi][ni][r2];
        const float h = v3 * v1 / (1.0f + expf(-v1));
        O[(size_t)mg*NF2 + n0 + wn + ni*16 + (l&15)] = f2b(h);
      }
    }
  }
}

// ---- MERGED down: bid<512 -> sdown (128x128, z=bid&7); else rdown (fused fp32 B) ----
__global__ __launch_bounds__(256, 2) void down_all_kernel(
    const u16* __restrict__ Hb, const u16* __restrict__ W2t, float* __restrict__ Sbuf,
    const u16* __restrict__ Gb, const float* __restrict__ W2r, float* __restrict__ Ebuf,
    const int* __restrict__ counts, const int* __restrict__ offsets)
{
  __shared__ alignas(16) char LDSu[40960];
  const int bid = blockIdx.x;
  const int tid = threadIdx.x, w = tid>>6, l = tid&63;

  if (bid < 512){
    // ---------- sdown ----------
    const int e = bid & 7;
    const int r = bid >> 3;
    const int xt = r >> 3;
    const int yt = r & 7;
    const int m0 = yt * 128;
    const int n0 = xt * 128;
    const u16* A  = Hb  + (size_t)e*TK*NF3;
    const u16* W2 = W2t + (size_t)e*HD*NF3;
    char* Alc = LDSu;            // 16KB
    char* Blc = LDSu + 16384;    // 16KB

    const int wm = (w>>1)*64, wn = (w&1)*64;
    const u16 *asrc[4], *bsrc[4];
    #pragma unroll
    for (int p=0;p<4;p++){
      const int id = p*256 + tid;
      const int row = id>>3;
      const int chunk = (id&7)^(row&7);
      asrc[p] = A  + (size_t)(m0+row)*NF3 + chunk*8;
      bsrc[p] = W2 + (size_t)(n0+row)*NF3 + chunk*8;
    }

    f32x4 acc[4][4] = {};
    constexpr int NT = NF3/64;
    for (int t=0; t<NT; ++t){
      #pragma unroll
      for (int p=0;p<4;p++) GLDS16(asrc[p] + t*64, Alc + ((p*256+tid)<<4));
      #pragma unroll
      for (int p=0;p<4;p++) GLDS16(bsrc[p] + t*64, Blc + ((p*256+tid)<<4));
      __syncthreads();
      #pragma unroll
      for (int kh=0;kh<2;kh++){
        bf16x8 af[4], bfr[4];
        #pragma unroll
        for (int mi=0;mi<4;mi++)
          af[mi]  = *(const bf16x8*)(Alc + swz8(wm + mi*16 + (l&15), kh*4 + (l>>4)));
        #pragma unroll
        for (int ni=0;ni<4;ni++)
          bfr[ni] = *(const bf16x8*)(Blc + swz8(wn + ni*16 + (l&15), kh*4 + (l>>4)));
        #pragma unroll
        for (int mi=0;mi<4;mi++){
          #pragma unroll
          for (int ni=0;ni<4;ni++)
            acc[mi][ni] = __builtin_amdgcn_mfma_f32_16x16x32_bf16(af[mi], bfr[ni], acc[mi][ni], 0,0,0);
        }
      }
      __syncthreads();
    }

    #pragma unroll
    for (int mi=0;mi<4;mi++){
      #pragma unroll
      for (int ni=0;ni<4;ni++){
        #pragma unroll
        for (int r2=0;r2<4;r2++){
          const int row = wm + mi*16 + ((l>>4)<<2) + r2;
          const int col = n0 + wn + ni*16 + (l&15);
          Sbuf[((size_t)e*TK + m0+row)*HD + col] = acc[mi][ni][r2];
        }
      }
    }
  } else {
    // ---------- rdown (fused fp32-B transpose-convert) ----------
    const int rb = bid - 512;
    const int z  = rb >> 7;                  // /128
    const int rem = rb & 127;
    const int yt = rem >> 4, xt = rem & 15;
    const int m0 = yt * 128;
    const int n0 = xt * 64;
    const int Meff = counts[z];
    if (m0 >= Meff) return;
    const int off = offsets[z];
    const u16* A = Gb + (size_t)off*NF2;
    const float* W2 = W2r + (size_t)z*NF2*HD;
    char* Alc = LDSu;            // 16KB
    char* Scc = LDSu + 16384;    // 16KB fp32 scratch
    char* Blc = LDSu + 32768;    // 8KB

    const int wm = (w>>1)*64, wn = (w&1)*32;
    int aofs[4];
    #pragma unroll
    for (int p=0;p<4;p++){
      const int id = p*256 + tid;
      const int row = id>>3;
      const int chunk = (id&7) ^ (row&7);
      int mg = m0 + row; if (mg >= Meff) mg = Meff-1;
      aofs[p] = mg*NF2 + chunk*8;
    }
    int bofs[4];
    #pragma unroll
    for (int p=0;p<4;p++){
      const int id = p*256 + tid;
      const int k = id>>4, c = id&15;
      bofs[p] = k*HD + n0 + chunkperm(c, k)*4;
    }

    f32x4 acc[4][2] = {};
    constexpr int NT = NF2/64;
    for (int t=0; t<NT; ++t){
      #pragma unroll
      for (int p=0;p<4;p++) GLDS16(A + aofs[p] + t*64, Alc + ((p*256+tid)<<4));
      #pragma unroll
      for (int p=0;p<4;p++) GLDS16(W2 + bofs[p] + (size_t)t*64*HD, Scc + ((p*256+tid)<<4));
      __syncthreads();
      {
        const int nq = tid&15, kq = tid>>4;
        float4 v[4];
        #pragma unroll
        for (int i=0;i<4;i++) v[i] = *(const float4*)(Scc + scrofs(kq*4+i, nq));
        #pragma unroll
        for (int j=0;j<4;j++){
          const int n = nq*4+j;
          uint2 wv;
          wv.x = pk2(v[0][j], v[1][j]);
          wv.y = pk2(v[2][j], v[3][j]);
          *(uint2*)(Blc + n*128 + (((kq>>1)^((n>>1)&7))<<4) + ((kq&1)<<3)) = wv;
        }
      }
      __syncthreads();
      #pragma unroll
      for (int kh=0;kh<2;kh++){
        bf16x8 af[4], bfr[2];
        #pragma unroll
        for (int mi=0;mi<4;mi++)
          af[mi]  = *(const bf16x8*)(Alc + swz8(wm + mi*16 + (l&15), kh*4 + (l>>4)));
        #pragma unroll
        for (int ni=0;ni<2;ni++)
          bfr[ni] = *(const bf16x8*)(Blc + bswz(wn + ni*16 + (l&15), kh*4 + (l>>4)));
        #pragma unroll
        for (int mi=0;mi<4;mi++){
          #pragma unroll
          for (int ni=0;ni<2;ni++)
            acc[mi][ni] = __builtin_amdgcn_mfma_f32_16x16x32_bf16(af[mi], bfr[ni], acc[mi][ni], 0,0,0);
        }
      }
      __syncthreads();
    }

    #pragma unroll
    for (int mi=0;mi<4;mi++){
      #pragma unroll
      for (int ni=0;ni<2;ni++){
        #pragma unroll
        for (int r2=0;r2<4;r2++){
          const int row = wm + mi*16 + ((l>>4)<<2) + r2;
          const int mg  = m0 + row;
          if (mg >= Meff) continue;
          const int col = n0 + wn + ni*16 + (l&15);
          Ebuf[((size_t)off+mg)*HD + col] = acc[mi][ni][r2];
        }
      }
    }
  }
}

// ---- combine ----
__global__ __launch_bounds__(256) void combine_kernel(
    const float* __restrict__ x, const float* __restrict__ Sbuf,
    const float* __restrict__ Ebuf, const float* __restrict__ wts,
    const int* __restrict__ slot_of, float* __restrict__ out)
{
  const int t = blockIdx.x, tid = threadIdx.x;
  float4 o = ((const float4*)(x + (size_t)t*HD))[tid];
  float4 s = make_float4(0.f,0.f,0.f,0.f);
  #pragma unroll
  for (int e=0;e<NSH;e++){
    const float4 v = ((const float4*)(Sbuf + ((size_t)e*TK + t)*HD))[tid];
    s.x+=v.x; s.y+=v.y; s.z+=v.z; s.w+=v.w;
  }
  o.x += 0.125f*s.x; o.y += 0.125f*s.y; o.z += 0.125f*s.z; o.w += 0.125f*s.w;
  #pragma unroll
  for (int k=0;k<KSEL;k++){
    const float wgt = wts[t*KSEL+k];
    const int slot  = slot_of[t*KSEL+k];
    const float4 v = ((const float4*)(Ebuf + (size_t)slot*HD))[tid];
    o.x += wgt*v.x; o.y += wgt*v.y; o.z += wgt*v.z; o.w += wgt*v.w;
  }
  ((float4*)(out + (size_t)t*HD))[tid] = o;
}

// ---------------- launch ----------------

extern "C" void kernel_launch(void* const* d_in, const int* in_sizes, int n_in,
                              void* d_out, int out_size, void* d_ws, size_t ws_size,
                              hipStream_t stream)
{
  const float* x   = (const float*)d_in[0];
  const float* sn  = (const float*)d_in[1];
  const float* sw1 = (const float*)d_in[2];
  const float* sw2 = (const float*)d_in[3];
  const float* sw3 = (const float*)d_in[4];
  const float* rw1 = (const float*)d_in[5];
  const float* rw2 = (const float*)d_in[6];
  const float* rw3 = (const float*)d_in[7];
  const float* rd  = (const float*)d_in[8];
  const float* ru  = (const float*)d_in[9];
  float* out = (float*)d_out;

  char* ws = (char*)d_ws;
  u16* xb    = (u16*)(ws);                               // 2 MB
  u16* Hbuf  = (u16*)(ws + ((size_t)18<<20));            // 48 MB
  u16* Gbuf  = (u16*)(ws + ((size_t)66<<20));            // 16 MB
  char* aux  = ws + ((size_t)82<<20);
  int*   sel    = (int*)(aux);
  float* wts    = (float*)(aux + 16384);
  int*   counts = (int*)(aux + 32768);
  int*   offs   = (int*)(aux + 33024);
  int*   curs   = (int*)(aux + 33280);
  int*   tok_of = (int*)(aux + 34816);
  float* wt_of  = (float*)(aux + 34816 + 16384);
  int*   slot_of= (int*)(aux + 34816 + 32768);
  float* rvec   = (float*)(aux + 34816 + 49152);
  const size_t WSLICE   = (size_t)NSH*NF3*HD*2;
  const size_t WBASE    = (size_t)84<<20;
  const size_t SBUF_OFF = WBASE + 3*WSLICE;
  const size_t SBUF_SZ  = (size_t)NSH*TK*HD*4;
  const size_t EBUF_OFF = SBUF_OFF + SBUF_SZ;
  u16* sw1t = (u16*)(ws + WBASE);
  u16* sw3t = (u16*)(ws + WBASE + WSLICE);
  u16* sw2t = (u16*)(ws + WBASE + 2*WSLICE);
  float* Sbuf = (float*)(ws + SBUF_OFF);
  float* Ebuf = (float*)(ws + EBUF_OFF);

  hipLaunchKernelGGL(init_kernel, dim3(1), dim3(64), 0, stream, counts, curs);
  // fused rms+router
  hipLaunchKernelGGL(rmsrouter_kernel, dim3(TK), dim3(256), 0, stream,
                     x, rd, ru, xb, rvec, sel, wts, counts);
  // scatter with local scan (+ global offsets + loss from block 0)
  hipLaunchKernelGGL(scatter2_kernel, dim3(16), dim3(256), 0, stream,
                     sel, wts, counts, curs, offs, tok_of, wt_of, slot_of,
                     out + (size_t)TK*HD);
  // merged weight conversion (sw1+sn | sw3+sn | sw2)
  hipLaunchKernelGGL(convT_all_kernel, dim3(3*NSH*768), dim3(256), 0, stream,
                     sw1, sw3, sw2, sn, sw1t, sw3t, sw2t);
  // shared up
  hipLaunchKernelGGL(up2_kernel, dim3((NF3/64)*(TK/256)*NSH), dim3(256), 0, stream,
                     xb, sw1t, sw3t, Hbuf, rvec);
  // routed up
  hipLaunchKernelGGL(up3_kernel, dim3(NF2/64, 4, NEX), dim3(256), 0, stream,
                     xb, rw1, rw3, Gbuf, counts, offs, tok_of);
  // merged down (sdown 512 blocks + rdown 32*128 blocks)
  hipLaunchKernelGGL(down_all_kernel, dim3(512 + NEX*128), dim3(256), 0, stream,
                     Hbuf, sw2t, Sbuf, Gbuf, rw2, Ebuf, counts, offs);
  // combine
  hipLaunchKernelGGL(combine_kernel, dim3(TK), dim3(256), 0, stream,
                     x, Sbuf, Ebuf, wts, slot_of, out);
}

// Round 16
// 547.746 us; speedup vs baseline: 1.1415x; 1.0073x over previous
//
#include <hip/hip_runtime.h>
#include <hip/hip_bf16.h>
#include <math.h>

#define TK 1024
#define HD 1024
#define NF3 3072
#define NF2 2048
#define NSH 8
#define NEX 32
#define KSEL 4
#define RRK 64

typedef short bf16x8 __attribute__((ext_vector_type(8)));
typedef float f32x4 __attribute__((ext_vector_type(4)));
typedef unsigned short u16;

__device__ __forceinline__ u16 f2b(float f){
  union{float f; unsigned u;} c; c.f=f;
  unsigned r = c.u + 0x7FFFu + ((c.u>>16)&1u);
  return (u16)(r>>16);
}

__device__ __forceinline__ unsigned pk2(float a, float b){
  __hip_bfloat162 h = __float22bfloat162_rn(float2{a, b});
  union{__hip_bfloat162 h; unsigned u;} c; c.h = h; return c.u;
}

__device__ __forceinline__ int swz8(int row, int c){
  return row*128 + ((c ^ (row&7))<<4);
}
__device__ __forceinline__ int bswz(int row, int c){
  return row*128 + ((c ^ ((row>>1)&7))<<4);
}
__device__ __forceinline__ int scrofs(int k, int nq){
  return k*256 + (((nq&8) | ((nq&7)^(k&7)))<<4);
}
__device__ __forceinline__ int chunkperm(int c, int k){
  return (c&8) | ((c&7)^(k&7));
}

#define GLDS16(gptr, lptr) \
  __builtin_amdgcn_global_load_lds((const __attribute__((address_space(1))) unsigned*)(gptr), \
                                   (__attribute__((address_space(3))) unsigned*)(lptr), 16, 0, 0)

// ---------------- small kernels ----------------

__global__ void init_kernel(int* counts, int* cursors){
  int i = threadIdx.x;
  if (i < NEX){ counts[i]=0; cursors[i]=0; }
}

// FUSED rms + router
__global__ __launch_bounds__(256) void rmsrouter_kernel(
    const float* __restrict__ x, const float* __restrict__ rd, const float* __restrict__ ru,
    u16* __restrict__ xb, float* __restrict__ rvec,
    int* __restrict__ sel, float* __restrict__ wts, int* __restrict__ counts)
{
  const int t = blockIdx.x, tid = threadIdx.x;
  __shared__ float xl[HD];
  __shared__ float red[4];
  __shared__ float xr4[RRK][4];
  __shared__ float lg[NEX];

  const float4 v = ((const float4*)(x + (size_t)t*HD))[tid];
  xl[tid*4+0]=v.x; xl[tid*4+1]=v.y; xl[tid*4+2]=v.z; xl[tid*4+3]=v.w;
  float ss = v.x*v.x + v.y*v.y + v.z*v.z + v.w*v.w;
  #pragma unroll
  for (int m=32;m>=1;m>>=1) ss += __shfl_xor(ss, m);
  if ((tid&63)==0) red[tid>>6]=ss;
  __syncthreads();
  const float r = rsqrtf((red[0]+red[1]+red[2]+red[3])*(1.0f/HD) + 1e-6f);
  if (tid==0) rvec[t] = r;
  ushort4 o; o.x=f2b(v.x); o.y=f2b(v.y); o.z=f2b(v.z); o.w=f2b(v.w);
  ((ushort4*)(xb + (size_t)t*HD))[tid] = o;

  const int rr = tid & 63, q = tid >> 6;
  float acc = 0.f;
  const int h0 = q*256;
  for (int h=h0; h<h0+256; ++h) acc += xl[h]*rd[h*RRK + rr];
  xr4[rr][q] = acc;
  __syncthreads();
  if (tid < RRK) xr4[tid][0] = xr4[tid][0]+xr4[tid][1]+xr4[tid][2]+xr4[tid][3];
  __syncthreads();
  if (tid < NEX){
    float a=0.f;
    for (int rk=0; rk<RRK; ++rk) a += xr4[rk][0]*ru[rk*NEX + tid];
    lg[tid]=a;
  }
  __syncthreads();
  if (tid==0){
    int   sk[KSEL]; float val[KSEL]; unsigned used=0;
    for (int k=0;k<KSEL;k++){
      float best=-1e30f; int bi=0;
      for (int e=0;e<NEX;e++){
        if (used & (1u<<e)) continue;
        if (lg[e] > best){ best=lg[e]; bi=e; }
      }
      used |= (1u<<bi); sk[k]=bi; val[k]=best;
    }
    const float m = val[0];
    float w[KSEL], s=0.f;
    for (int k=0;k<KSEL;k++){ w[k]=expf(val[k]-m); s+=w[k]; }
    for (int k=0;k<KSEL;k++){
      sel[t*KSEL+k]=sk[k]; wts[t*KSEL+k]=w[k]/s;
      atomicAdd(&counts[sk[k]], 1);
    }
  }
}

// scatter with LOCAL scan; block 0 writes global offsets + loss.
__global__ void scatter2_kernel(const int* __restrict__ sel, const float* __restrict__ wts,
                                const int* __restrict__ counts, int* __restrict__ cursors,
                                int* __restrict__ offsets,
                                int* __restrict__ tok_of, float* __restrict__ wt_of,
                                int* __restrict__ slot_of, float* __restrict__ out_loss)
{
  __shared__ int offs_l[NEX];
  if (threadIdx.x==0){
    int off=0; float var=0.f;
    for (int e=0;e<NEX;e++){
      offs_l[e]=off;
      if (blockIdx.x==0) offsets[e]=off;
      off+=counts[e];
      float d = (float)counts[e] - 128.0f;
      var += d*d;
    }
    if (blockIdx.x==0) out_loss[0] = var * (1.0f/31.0f);
  }
  __syncthreads();
  const int id = blockIdx.x*256 + threadIdx.x;
  const int e = sel[id];
  const int pos = atomicAdd(&cursors[e], 1);
  const int slot = offs_l[e] + pos;
  tok_of[slot] = id >> 2;
  wt_of[slot]  = wts[id];
  slot_of[id]  = slot;
}

// MERGED transpose-convert for sw1(+sn), sw3(+sn), sw2.
__global__ __launch_bounds__(256) void convT_all_kernel(
    const float* __restrict__ sw1, const float* __restrict__ sw3, const float* __restrict__ sw2,
    const float* __restrict__ snb,
    u16* __restrict__ sw1t, u16* __restrict__ sw3t, u16* __restrict__ sw2t)
{
  const int bid = blockIdx.x;
  const int mat = bid / (NSH*768);
  const int rem = bid - mat*(NSH*768);
  const int z = rem / 768, tt = rem - z*768;
  int K, N, n0, k0; const float* src; u16* dst; const float* snp = nullptr;
  if (mat < 2){
    K = HD; N = NF3;
    n0 = (tt % 48)*64; k0 = (tt / 48)*64;
    src = (mat ? sw3 : sw1) + (size_t)z*K*N;
    dst = (mat ? sw3t : sw1t) + (size_t)z*N*K;
    snp = snb + (size_t)z*HD + k0;
  } else {
    K = NF3; N = HD;
    n0 = (tt % 16)*64; k0 = (tt / 16)*64;
    src = sw2 + (size_t)z*K*N;
    dst = sw2t + (size_t)z*N*K;
  }
  __shared__ float tile[64][65];
  const int t = threadIdx.x;
  const int kr = t>>4, nc = t&15;
  #pragma unroll
  for (int i=0;i<4;i++){
    const int k = kr + 16*i;
    const float4 v = *(const float4*)(src + (size_t)(k0+k)*N + n0 + nc*4);
    tile[k][nc*4+0]=v.x; tile[k][nc*4+1]=v.y; tile[k][nc*4+2]=v.z; tile[k][nc*4+3]=v.w;
  }
  __syncthreads();
  const int nr = t>>3, kc = t&7;
  float sv[8];
  #pragma unroll
  for (int j=0;j<8;j++) sv[j] = snp ? snp[kc*8+j] : 1.0f;
  #pragma unroll
  for (int p=0;p<2;p++){
    const int n = nr + 32*p;
    unsigned d0 = pk2(tile[kc*8+0][n]*sv[0], tile[kc*8+1][n]*sv[1]);
    unsigned d1 = pk2(tile[kc*8+2][n]*sv[2], tile[kc*8+3][n]*sv[3]);
    unsigned d2 = pk2(tile[kc*8+4][n]*sv[4], tile[kc*8+5][n]*sv[5]);
    unsigned d3 = pk2(tile[kc*8+6][n]*sv[6], tile[kc*8+7][n]*sv[7]);
    *(uint4*)(dst + (size_t)(n0+n)*K + k0 + kc*8) = make_uint4(d0,d1,d2,d3);
  }
}

// ---- shared up: BM=256, dual-B 64 (W1|W3), dual gload_lds, 2-barrier loop ----
__global__ __launch_bounds__(256, 2) void up2_kernel(
    const u16* __restrict__ xb, const u16* __restrict__ W1t, const u16* __restrict__ W3t,
    u16* __restrict__ Ob, const float* __restrict__ rvec)
{
  const int b = blockIdx.x;
  const int z = b & 7;
  const int r = b >> 3;
  const int xt = r >> 2;
  const int yt = r & 3;
  const int m0 = yt * 256;
  const int n0 = xt * 64;
  const u16* W1 = W1t + (size_t)z*NF3*HD;
  const u16* W3 = W3t + (size_t)z*NF3*HD;
  u16* O = Ob + (size_t)z*TK*NF3;

  __shared__ alignas(16) u16 Al[256*64];
  __shared__ alignas(16) u16 Bl[128*64];
  char* Alc = (char*)Al; char* Blc = (char*)Bl;

  const int tid = threadIdx.x, w = tid>>6, l = tid&63;
  const int wm = (w>>1)*128, wn = (w&1)*32;

  const u16 *asrc[8], *bsrc[4];
  #pragma unroll
  for (int p=0;p<8;p++){
    const int id = p*256 + tid;
    const int row = id>>3;
    const int chunk = (id&7) ^ (row&7);
    asrc[p] = xb + (size_t)(m0+row)*HD + chunk*8;
  }
  #pragma unroll
  for (int p=0;p<4;p++){
    const int id = p*256 + tid;
    const int row = id>>3;
    const int chunk = (id&7) ^ (row&7);
    bsrc[p] = ((row<64) ? (W1 + (size_t)(n0+row)*HD) : (W3 + (size_t)(n0+row-64)*HD)) + chunk*8;
  }

  f32x4 acc1[8][2] = {}; f32x4 acc3[8][2] = {};

  auto issue = [&](int ke){
    #pragma unroll
    for (int p=0;p<8;p++) GLDS16(asrc[p] + ke, Alc + ((p*256+tid)<<4));
    #pragma unroll
    for (int p=0;p<4;p++) GLDS16(bsrc[p] + ke, Blc + ((p*256+tid)<<4));
  };
  auto compute = [&](){
    #pragma unroll
    for (int kh=0;kh<2;kh++){
      bf16x8 af[8], b1[2], b3[2];
      #pragma unroll
      for (int mi=0;mi<8;mi++)
        af[mi] = *(const bf16x8*)(Alc + swz8(wm + mi*16 + (l&15), kh*4 + (l>>4)));
      #pragma unroll
      for (int ni=0;ni<2;ni++){
        b1[ni] = *(const bf16x8*)(Blc + swz8(     wn + ni*16 + (l&15), kh*4 + (l>>4)));
        b3[ni] = *(const bf16x8*)(Blc + swz8(64 + wn + ni*16 + (l&15), kh*4 + (l>>4)));
      }
      #pragma unroll
      for (int mi=0;mi<8;mi++){
        #pragma unroll
        for (int ni=0;ni<2;ni++){
          acc1[mi][ni] = __builtin_amdgcn_mfma_f32_16x16x32_bf16(af[mi], b1[ni], acc1[mi][ni], 0,0,0);
          acc3[mi][ni] = __builtin_amdgcn_mfma_f32_16x16x32_bf16(af[mi], b3[ni], acc3[mi][ni], 0,0,0);
        }
      }
    }
  };

  constexpr int NT = HD/64;
  for (int t=0; t<NT; ++t){
    issue(t*64);
    __syncthreads();
    compute();
    __syncthreads();
  }

  #pragma unroll
  for (int mi=0;mi<8;mi++){
    #pragma unroll
    for (int ni=0;ni<2;ni++){
      #pragma unroll
      for (int r2=0;r2<4;r2++){
        const int row = wm + mi*16 + ((l>>4)<<2) + r2;
        const float rr = rvec[m0+row];
        const float v1 = rr*acc1[mi][ni][r2], v3 = rr*acc3[mi][ni][r2];
        const float h = v3 * v1 / (1.0f + expf(-v1));
        O[(size_t)(m0+row)*NF3 + n0 + wn + ni*16 + (l&15)] = f2b(h);
      }
    }
  }
}

// ---- routed up, fused fp32-B transpose-convert (bswz) ----
__global__ __launch_bounds__(256, 2) void up3_kernel(
    const u16* __restrict__ xb, const float* __restrict__ W1b, const float* __restrict__ W3b,
    u16* __restrict__ Ob, const int* __restrict__ counts, const int* __restrict__ offsets,
    const int* __restrict__ tok_of)
{
  const int z  = blockIdx.z;
  const int m0 = blockIdx.y * 256;
  const int n0 = blockIdx.x * 64;
  const int Meff = counts[z];
  if (m0 >= Meff) return;
  const int off = offsets[z];
  const int* toks = tok_of + off;
  const float* W1 = W1b + (size_t)z*HD*NF2;
  const float* W3 = W3b + (size_t)z*HD*NF2;
  u16* O = Ob + (size_t)off*NF2;

  __shared__ alignas(16) u16   Al[256*64];
  __shared__ alignas(16) float Scr[2*64*64];
  __shared__ alignas(16) u16   Bl[2*64*64];
  char* Alc = (char*)Al; char* Blc = (char*)Bl; char* Scc = (char*)Scr;

  const int tid = threadIdx.x, w = tid>>6, l = tid&63;
  const int wm = (w>>1)*128, wn = (w&1)*32;

  int aofs[8];
  #pragma unroll
  for (int p=0;p<8;p++){
    const int id = p*256 + tid;
    const int row = id>>3;
    const int chunk = (id&7) ^ (row&7);
    int mg = m0 + row;
    mg = toks[(mg < Meff) ? mg : (Meff-1)];
    aofs[p] = mg*HD + chunk*8;
  }
  int bofs[8];
  #pragma unroll
  for (int p=0;p<8;p++){
    const int id = (p&3)*256 + tid;
    const int k = id>>4, c = id&15;
    bofs[p] = k*NF2 + n0 + chunkperm(c, k)*4;
  }

  f32x4 acc1[8][2] = {}; f32x4 acc3[8][2] = {};

  constexpr int NT = HD/64;
  for (int t=0; t<NT; ++t){
    #pragma unroll
    for (int p=0;p<8;p++) GLDS16(xb + aofs[p] + t*64, Alc + ((p*256+tid)<<4));
    #pragma unroll
    for (int p=0;p<4;p++) GLDS16(W1 + bofs[p] + (size_t)t*64*NF2, Scc + ((p*256+tid)<<4));
    #pragma unroll
    for (int p=4;p<8;p++) GLDS16(W3 + bofs[p] + (size_t)t*64*NF2, Scc + 16384 + (((p-4)*256+tid)<<4));
    __syncthreads();

    {
      const int nq = tid&15, kq = tid>>4;
      #pragma unroll
      for (int m2=0;m2<2;m2++){
        const char* sc = Scc + m2*16384;
        char* bd = Blc + m2*8192;
        float4 v[4];
        #pragma unroll
        for (int i=0;i<4;i++) v[i] = *(const float4*)(sc + scrofs(kq*4+i, nq));
        #pragma unroll
        for (int j=0;j<4;j++){
          const int n = nq*4+j;
          uint2 wv;
          wv.x = pk2(v[0][j], v[1][j]);
          wv.y = pk2(v[2][j], v[3][j]);
          *(uint2*)(bd + n*128 + (((kq>>1)^((n>>1)&7))<<4) + ((kq&1)<<3)) = wv;
        }
      }
    }
    __syncthreads();

    #pragma unroll
    for (int kh=0;kh<2;kh++){
      bf16x8 af[8], b1[2], b3[2];
      #pragma unroll
      for (int mi=0;mi<8;mi++)
        af[mi] = *(const bf16x8*)(Alc + swz8(wm + mi*16 + (l&15), kh*4 + (l>>4)));
      #pragma unroll
      for (int ni=0;ni<2;ni++){
        b1[ni] = *(const bf16x8*)(Blc +        bswz(wn + ni*16 + (l&15), kh*4 + (l>>4)));
        b3[ni] = *(const bf16x8*)(Blc + 8192 + bswz(wn + ni*16 + (l&15), kh*4 + (l>>4)));
      }
      #pragma unroll
      for (int mi=0;mi<8;mi++){
        #pragma unroll
        for (int ni=0;ni<2;ni++){
          acc1[mi][ni] = __builtin_amdgcn_mfma_f32_16x16x32_bf16(af[mi], b1[ni], acc1[mi][ni], 0,0,0);
          acc3[mi][ni] = __builtin_amdgcn_mfma_f32_16x16x32_bf16(af[mi], b3[ni], acc3[mi][ni], 0,0,0);
        }
      }
    }
    __syncthreads();
  }

  #pragma unroll
  for (int mi=0;mi<8;mi++){
    #pragma unroll
    for (int ni=0;ni<2;ni++){
      #pragma unroll
      for (int r2=0;r2<4;r2++){
        const int row = wm + mi*16 + ((l>>4)<<2) + r2;
        const int mg  = m0 + row;
        if (mg >= Meff) continue;
        const float v1 = acc1[mi][ni][r2], v3 = acc3[mi][ni][r2];
        const float h = v3 * v1 / (1.0f + expf(-v1));
        O[(size_t)mg*NF2 + n0 + wn + ni*16 + (l&15)] = f2b(h);
      }
    }
  }
}

// ---- MERGED down, 32KB LDS union -> 5 blocks/CU.
// bid<512: sdown (A 16K | B 16K). else: rdown with A/Scr TIME-MULTIPLEXED in [0,16K):
//   W-DMA->Scr, bar, transpose Scr->B(@16K), bar, A-DMA->same 16K, bar, MFMA, bar.
__global__ __launch_bounds__(256, 2) void down_all_kernel(
    const u16* __restrict__ Hb, const u16* __restrict__ W2t, float* __restrict__ Sbuf,
    const u16* __restrict__ Gb, const float* __restrict__ W2r, float* __restrict__ Ebuf,
    const int* __restrict__ counts, const int* __restrict__ offsets)
{
  __shared__ alignas(16) char LDSu[32768];
  const int bid = blockIdx.x;
  const int tid = threadIdx.x, w = tid>>6, l = tid&63;

  if (bid < 512){
    // ---------- sdown ----------
    const int e = bid & 7;
    const int r = bid >> 3;
    const int xt = r >> 3;
    const int yt = r & 7;
    const int m0 = yt * 128;
    const int n0 = xt * 128;
    const u16* A  = Hb  + (size_t)e*TK*NF3;
    const u16* W2 = W2t + (size_t)e*HD*NF3;
    char* Alc = LDSu;
    char* Blc = LDSu + 16384;

    const int wm = (w>>1)*64, wn = (w&1)*64;
    const u16 *asrc[4], *bsrc[4];
    #pragma unroll
    for (int p=0;p<4;p++){
      const int id = p*256 + tid;
      const int row = id>>3;
      const int chunk = (id&7)^(row&7);
      asrc[p] = A  + (size_t)(m0+row)*NF3 + chunk*8;
      bsrc[p] = W2 + (size_t)(n0+row)*NF3 + chunk*8;
    }

    f32x4 acc[4][4] = {};
    constexpr int NT = NF3/64;
    for (int t=0; t<NT; ++t){
      #pragma unroll
      for (int p=0;p<4;p++) GLDS16(asrc[p] + t*64, Alc + ((p*256+tid)<<4));
      #pragma unroll
      for (int p=0;p<4;p++) GLDS16(bsrc[p] + t*64, Blc + ((p*256+tid)<<4));
      __syncthreads();
      #pragma unroll
      for (int kh=0;kh<2;kh++){
        bf16x8 af[4], bfr[4];
        #pragma unroll
        for (int mi=0;mi<4;mi++)
          af[mi]  = *(const bf16x8*)(Alc + swz8(wm + mi*16 + (l&15), kh*4 + (l>>4)));
        #pragma unroll
        for (int ni=0;ni<4;ni++)
          bfr[ni] = *(const bf16x8*)(Blc + swz8(wn + ni*16 + (l&15), kh*4 + (l>>4)));
        #pragma unroll
        for (int mi=0;mi<4;mi++){
          #pragma unroll
          for (int ni=0;ni<4;ni++)
            acc[mi][ni] = __builtin_amdgcn_mfma_f32_16x16x32_bf16(af[mi], bfr[ni], acc[mi][ni], 0,0,0);
        }
      }
      __syncthreads();
    }

    #pragma unroll
    for (int mi=0;mi<4;mi++){
      #pragma unroll
      for (int ni=0;ni<4;ni++){
        #pragma unroll
        for (int r2=0;r2<4;r2++){
          const int row = wm + mi*16 + ((l>>4)<<2) + r2;
          const int col = n0 + wn + ni*16 + (l&15);
          Sbuf[((size_t)e*TK + m0+row)*HD + col] = acc[mi][ni][r2];
        }
      }
    }
  } else {
    // ---------- rdown (fused fp32-B transpose; A/Scr time-multiplexed) ----------
    const int rb = bid - 512;
    const int z  = rb >> 7;
    const int rem = rb & 127;
    const int yt = rem >> 4, xt = rem & 15;
    const int m0 = yt * 128;
    const int n0 = xt * 64;
    const int Meff = counts[z];
    if (m0 >= Meff) return;
    const int off = offsets[z];
    const u16* A = Gb + (size_t)off*NF2;
    const float* W2 = W2r + (size_t)z*NF2*HD;
    char* Alc = LDSu;            // 16KB — aliases Scc (time-multiplexed)
    char* Scc = LDSu;            // 16KB fp32 scratch
    char* Blc = LDSu + 16384;    // 8KB

    const int wm = (w>>1)*64, wn = (w&1)*32;
    int aofs[4];
    #pragma unroll
    for (int p=0;p<4;p++){
      const int id = p*256 + tid;
      const int row = id>>3;
      const int chunk = (id&7) ^ (row&7);
      int mg = m0 + row; if (mg >= Meff) mg = Meff-1;
      aofs[p] = mg*NF2 + chunk*8;
    }
    int bofs[4];
    #pragma unroll
    for (int p=0;p<4;p++){
      const int id = p*256 + tid;
      const int k = id>>4, c = id&15;
      bofs[p] = k*HD + n0 + chunkperm(c, k)*4;
    }

    f32x4 acc[4][2] = {};
    constexpr int NT = NF2/64;
    for (int t=0; t<NT; ++t){
      // 1) W fp32 -> Scr
      #pragma unroll
      for (int p=0;p<4;p++) GLDS16(W2 + bofs[p] + (size_t)t*64*HD, Scc + ((p*256+tid)<<4));
      __syncthreads();
      // 2) transpose-convert Scr -> B
      {
        const int nq = tid&15, kq = tid>>4;
        float4 v[4];
        #pragma unroll
        for (int i=0;i<4;i++) v[i] = *(const float4*)(Scc + scrofs(kq*4+i, nq));
        #pragma unroll
        for (int j=0;j<4;j++){
          const int n = nq*4+j;
          uint2 wv;
          wv.x = pk2(v[0][j], v[1][j]);
          wv.y = pk2(v[2][j], v[3][j]);
          *(uint2*)(Blc + n*128 + (((kq>>1)^((n>>1)&7))<<4) + ((kq&1)<<3)) = wv;
        }
      }
      __syncthreads();          // Scr reads done -> region free for A
      // 3) A bf16 -> same 16KB region
      #pragma unroll
      for (int p=0;p<4;p++) GLDS16(A + aofs[p] + t*64, Alc + ((p*256+tid)<<4));
      __syncthreads();
      // 4) MFMA
      #pragma unroll
      for (int kh=0;kh<2;kh++){
        bf16x8 af[4], bfr[2];
        #pragma unroll
        for (int mi=0;mi<4;mi++)
          af[mi]  = *(const bf16x8*)(Alc + swz8(wm + mi*16 + (l&15), kh*4 + (l>>4)));
        #pragma unroll
        for (int ni=0;ni<2;ni++)
          bfr[ni] = *(const bf16x8*)(Blc + bswz(wn + ni*16 + (l&15), kh*4 + (l>>4)));
        #pragma unroll
        for (int mi=0;mi<4;mi++){
          #pragma unroll
          for (int ni=0;ni<2;ni++)
            acc[mi][ni] = __builtin_amdgcn_mfma_f32_16x16x32_bf16(af[mi], bfr[ni], acc[mi][ni], 0,0,0);
        }
      }
      __syncthreads();          // MFMA reads done before next W DMA overwrites
    }

    #pragma unroll
    for (int mi=0;mi<4;mi++){
      #pragma unroll
      for (int ni=0;ni<2;ni++){
        #pragma unroll
        for (int r2=0;r2<4;r2++){
          const int row = wm + mi*16 + ((l>>4)<<2) + r2;
          const int mg  = m0 + row;
          if (mg >= Meff) continue;
          const int col = n0 + wn + ni*16 + (l&15);
          Ebuf[((size_t)off+mg)*HD + col] = acc[mi][ni][r2];
        }
      }
    }
  }
}

// ---- combine ----
__global__ __launch_bounds__(256) void combine_kernel(
    const float* __restrict__ x, const float* __restrict__ Sbuf,
    const float* __restrict__ Ebuf, const float* __restrict__ wts,
    const int* __restrict__ slot_of, float* __restrict__ out)
{
  const int t = blockIdx.x, tid = threadIdx.x;
  float4 o = ((const float4*)(x + (size_t)t*HD))[tid];
  float4 s = make_float4(0.f,0.f,0.f,0.f);
  #pragma unroll
  for (int e=0;e<NSH;e++){
    const float4 v = ((const float4*)(Sbuf + ((size_t)e*TK + t)*HD))[tid];
    s.x+=v.x; s.y+=v.y; s.z+=v.z; s.w+=v.w;
  }
  o.x += 0.125f*s.x; o.y += 0.125f*s.y; o.z += 0.125f*s.z; o.w += 0.125f*s.w;
  #pragma unroll
  for (int k=0;k<KSEL;k++){
    const float wgt = wts[t*KSEL+k];
    const int slot  = slot_of[t*KSEL+k];
    const float4 v = ((const float4*)(Ebuf + (size_t)slot*HD))[tid];
    o.x += wgt*v.x; o.y += wgt*v.y; o.z += wgt*v.z; o.w += wgt*v.w;
  }
  ((float4*)(out + (size_t)t*HD))[tid] = o;
}

// ---------------- launch ----------------

extern "C" void kernel_launch(void* const* d_in, const int* in_sizes, int n_in,
                              void* d_out, int out_size, void* d_ws, size_t ws_size,
                              hipStream_t stream)
{
  const float* x   = (const float*)d_in[0];
  const float* sn  = (const float*)d_in[1];
  const float* sw1 = (const float*)d_in[2];
  const float* sw2 = (const float*)d_in[3];
  const float* sw3 = (const float*)d_in[4];
  const float* rw1 = (const float*)d_in[5];
  const float* rw2 = (const float*)d_in[6];
  const float* rw3 = (const float*)d_in[7];
  const float* rd  = (const float*)d_in[8];
  const float* ru  = (const float*)d_in[9];
  float* out = (float*)d_out;

  char* ws = (char*)d_ws;
  u16* xb    = (u16*)(ws);
  u16* Hbuf  = (u16*)(ws + ((size_t)18<<20));
  u16* Gbuf  = (u16*)(ws + ((size_t)66<<20));
  char* aux  = ws + ((size_t)82<<20);
  int*   sel    = (int*)(aux);
  float* wts    = (float*)(aux + 16384);
  int*   counts = (int*)(aux + 32768);
  int*   offs   = (int*)(aux + 33024);
  int*   curs   = (int*)(aux + 33280);
  int*   tok_of = (int*)(aux + 34816);
  float* wt_of  = (float*)(aux + 34816 + 16384);
  int*   slot_of= (int*)(aux + 34816 + 32768);
  float* rvec   = (float*)(aux + 34816 + 49152);
  const size_t WSLICE   = (size_t)NSH*NF3*HD*2;
  const size_t WBASE    = (size_t)84<<20;
  const size_t SBUF_OFF = WBASE + 3*WSLICE;
  const size_t SBUF_SZ  = (size_t)NSH*TK*HD*4;
  const size_t EBUF_OFF = SBUF_OFF + SBUF_SZ;
  u16* sw1t = (u16*)(ws + WBASE);
  u16* sw3t = (u16*)(ws + WBASE + WSLICE);
  u16* sw2t = (u16*)(ws + WBASE + 2*WSLICE);
  float* Sbuf = (float*)(ws + SBUF_OFF);
  float* Ebuf = (float*)(ws + EBUF_OFF);

  hipLaunchKernelGGL(init_kernel, dim3(1), dim3(64), 0, stream, counts, curs);
  hipLaunchKernelGGL(rmsrouter_kernel, dim3(TK), dim3(256), 0, stream,
                     x, rd, ru, xb, rvec, sel, wts, counts);
  hipLaunchKernelGGL(scatter2_kernel, dim3(16), dim3(256), 0, stream,
                     sel, wts, counts, curs, offs, tok_of, wt_of, slot_of,
                     out + (size_t)TK*HD);
  hipLaunchKernelGGL(convT_all_kernel, dim3(3*NSH*768), dim3(256), 0, stream,
                     sw1, sw3, sw2, sn, sw1t, sw3t, sw2t);
  hipLaunchKernelGGL(up2_kernel, dim3((NF3/64)*(TK/256)*NSH), dim3(256), 0, stream,
                     xb, sw1t, sw3t, Hbuf, rvec);
  hipLaunchKernelGGL(up3_kernel, dim3(NF2/64, 4, NEX), dim3(256), 0, stream,
                     xb, rw1, rw3, Gbuf, counts, offs, tok_of);
  hipLaunchKernelGGL(down_all_kernel, dim3(512 + NEX*128), dim3(256), 0, stream,
                     Hbuf, sw2t, Sbuf, Gbuf, rw2, Ebuf, counts, offs);
  hipLaunchKernelGGL(combine_kernel, dim3(TK), dim3(256), 0, stream,
                     x, Sbuf, Ebuf, wts, slot_of, out);
}